// Round 5
// baseline (1690.532 us; speedup 1.0000x reference)
//
#include <hip/hip_runtime.h>

#define N_NODES 500000
#define N_EDGES 2000000
#define N_GRAPHS 16384

#define SCAN_ELEMS 2048
#define SCAN_NBLK ((N_NODES + SCAN_ELEMS - 1) / SCAN_ELEMS)   // 245

typedef short bf16x8 __attribute__((ext_vector_type(8)));
typedef float f32x4 __attribute__((ext_vector_type(4)));
typedef unsigned short u16x8 __attribute__((ext_vector_type(8)));

__device__ __forceinline__ unsigned short f2bf_rne(float x) {
    unsigned int b = __float_as_uint(x);
    unsigned int r = (b + 0x7fffu + ((b >> 16) & 1u)) >> 16;
    return (unsigned short)r;
}
__device__ __forceinline__ float bf2f(unsigned short h) {
    return __uint_as_float(((unsigned int)h) << 16);
}
__device__ __forceinline__ void split_bf(float v, unsigned short& hi, unsigned short& lo) {
    hi = f2bf_rne(v);
    lo = f2bf_rne(v - bf2f(hi));
}

// ---------------- CSR build ----------------
__global__ __launch_bounds__(256) void k_zero_counts(int* counts) {
    int i = blockIdx.x * 256 + threadIdx.x;
    if (i < N_NODES) counts[i] = 0;
}
__global__ __launch_bounds__(256) void k_hist(const int* __restrict__ dst, int* __restrict__ counts) {
    int e = blockIdx.x * 256 + threadIdx.x;
    if (e < N_EDGES) atomicAdd(&counts[dst[e]], 1);
}
__global__ __launch_bounds__(256) void k_scan_reduce(const int* __restrict__ counts, int* __restrict__ bsum) {
    int b = blockIdx.x, t = threadIdx.x;
    int base_i = b * SCAN_ELEMS + t * 8;
    int s = 0;
    #pragma unroll
    for (int j = 0; j < 8; j++) { int i = base_i + j; if (i < N_NODES) s += counts[i]; }
    __shared__ int sh[256];
    sh[t] = s; __syncthreads();
    for (int off = 128; off > 0; off >>= 1) { if (t < off) sh[t] += sh[t + off]; __syncthreads(); }
    if (t == 0) bsum[b] = sh[0];
}
__global__ __launch_bounds__(256) void k_scan_bsum(const int* __restrict__ bsum, int* __restrict__ boff,
                                                   int* __restrict__ row_ptr) {
    __shared__ int sh[256];
    int t = threadIdx.x;
    int v = (t < SCAN_NBLK) ? bsum[t] : 0;
    sh[t] = v; __syncthreads();
    for (int off = 1; off < 256; off <<= 1) {
        int u = (t >= off) ? sh[t - off] : 0;
        __syncthreads();
        sh[t] += u; __syncthreads();
    }
    boff[t] = sh[t] - v;
    if (t == 255) row_ptr[N_NODES] = sh[255];
}
__global__ __launch_bounds__(256) void k_scan_final(const int* __restrict__ counts, const int* __restrict__ boff,
                                                    int* __restrict__ row_ptr, int* __restrict__ cursor,
                                                    float* __restrict__ dinv) {
    __shared__ int sh[256];
    int b = blockIdx.x, t = threadIdx.x;
    int base_i = b * SCAN_ELEMS + t * 8;
    int c[8]; int tsum = 0;
    #pragma unroll
    for (int j = 0; j < 8; j++) {
        int i = base_i + j;
        c[j] = (i < N_NODES) ? counts[i] : 0;
        tsum += c[j];
    }
    sh[t] = tsum; __syncthreads();
    for (int off = 1; off < 256; off <<= 1) {
        int u = (t >= off) ? sh[t - off] : 0;
        __syncthreads();
        sh[t] += u; __syncthreads();
    }
    int run = boff[b] + sh[t] - tsum;
    #pragma unroll
    for (int j = 0; j < 8; j++) {
        int i = base_i + j;
        if (i < N_NODES) {
            row_ptr[i] = run;
            cursor[i]  = run;
            dinv[i]    = rsqrtf((float)c[j] + 1.0f);
        }
        run += c[j];
    }
}
__global__ __launch_bounds__(256) void k_fill(const int* __restrict__ esrc, const int* __restrict__ edst,
                                              int* __restrict__ cursor, int* __restrict__ srcs) {
    int e = blockIdx.x * 256 + threadIdx.x;
    if (e >= N_EDGES) return;
    int d = edst[e];
    int pos = atomicAdd(&cursor[d], 1);
    srcs[pos] = esrc[e];
}
__global__ __launch_bounds__(256) void k_gstart(const int* __restrict__ batch, int* __restrict__ gstart) {
    int g = blockIdx.x * 256 + threadIdx.x;
    if (g > N_GRAPHS) return;
    if (g == N_GRAPHS) { gstart[g] = N_NODES; return; }
    int lo = 0, hi = N_NODES;
    while (lo < hi) { int mid = (lo + hi) >> 1; if (batch[mid] < g) lo = mid + 1; else hi = mid; }
    gstart[g] = lo;
}

// ---------------- conv1 tiled GEMM: C[M,128] = bf16(A[M,131] @ B[131,128]) ----------------
template<int KTOT>
__global__ __launch_bounds__(256) void k_gemm_conv1(const float* __restrict__ A,
                                                    const float* __restrict__ B,
                                                    unsigned short* __restrict__ C, int Mreal) {
    __shared__ float As[8][132];
    __shared__ float Bs[8][132];
    const int tid = threadIdx.x;
    const int bm = blockIdx.x;
    const int tr = (tid >> 4) << 3;
    const int tc = (tid & 15) << 3;
    float acc[8][8] = {};
    const int la_r = tid >> 1, la_c = (tid & 1) << 2;
    const int lb_r = tid >> 5, lb_c = (tid & 31) << 2;
    const int arow = min(bm * 128 + la_r, Mreal - 1);
    const float* Ap = A + (size_t)arow * KTOT + la_c;
    constexpr int KMAIN = (KTOT / 8) * 8;
    for (int k0 = 0; k0 < KMAIN; k0 += 8) {
        float4 a4 = *(const float4*)(Ap + k0);
        float4 b4 = *(const float4*)(B + (size_t)(k0 + lb_r) * 128 + lb_c);
        __syncthreads();
        As[la_c + 0][la_r] = a4.x;
        As[la_c + 1][la_r] = a4.y;
        As[la_c + 2][la_r] = a4.z;
        As[la_c + 3][la_r] = a4.w;
        *(float4*)&Bs[lb_r][lb_c] = b4;
        __syncthreads();
        #pragma unroll
        for (int k = 0; k < 8; k++) {
            float a[8], b[8];
            *(float4*)&a[0] = *(const float4*)&As[k][tr];
            *(float4*)&a[4] = *(const float4*)&As[k][tr + 4];
            *(float4*)&b[0] = *(const float4*)&Bs[k][tc];
            *(float4*)&b[4] = *(const float4*)&Bs[k][tc + 4];
            #pragma unroll
            for (int i = 0; i < 8; i++)
                #pragma unroll
                for (int j = 0; j < 8; j++)
                    acc[i][j] = fmaf(a[i], b[j], acc[i][j]);
        }
    }
    if (KTOT % 8 != 0) {
        constexpr int k0 = KMAIN;
        float av[4];
        #pragma unroll
        for (int j = 0; j < 4; j++) av[j] = (k0 + la_c + j < KTOT) ? Ap[k0 + j] : 0.0f;
        float4 b4 = {0.f, 0.f, 0.f, 0.f};
        if (k0 + lb_r < KTOT) b4 = *(const float4*)(B + (size_t)(k0 + lb_r) * 128 + lb_c);
        __syncthreads();
        As[la_c + 0][la_r] = av[0];
        As[la_c + 1][la_r] = av[1];
        As[la_c + 2][la_r] = av[2];
        As[la_c + 3][la_r] = av[3];
        *(float4*)&Bs[lb_r][lb_c] = b4;
        __syncthreads();
        #pragma unroll
        for (int k = 0; k < 8; k++) {
            float a[8], b[8];
            *(float4*)&a[0] = *(const float4*)&As[k][tr];
            *(float4*)&a[4] = *(const float4*)&As[k][tr + 4];
            *(float4*)&b[0] = *(const float4*)&Bs[k][tc];
            *(float4*)&b[4] = *(const float4*)&Bs[k][tc + 4];
            #pragma unroll
            for (int i = 0; i < 8; i++)
                #pragma unroll
                for (int j = 0; j < 8; j++)
                    acc[i][j] = fmaf(a[i], b[j], acc[i][j]);
        }
    }
    const int row0 = bm * 128 + tr;
    #pragma unroll
    for (int i = 0; i < 8; i++) {
        if (row0 + i < Mreal) {
            u16x8 o;
            #pragma unroll
            for (int j = 0; j < 8; j++) o[j] = f2bf_rne(acc[i][j]);
            *(u16x8*)(C + (size_t)(row0 + i) * 128 + tc) = o;
        }
    }
}

// ---------------- conv1 gather (bf16 in, fp32 accum, relu, bf16 out) ----------------
// r1[n] = relu(dinv[n]^2*h[n] + bc1 + sum_e dinv[s]*dinv[n]*h[s])
__global__ __launch_bounds__(256) void k_gather1(const unsigned short* __restrict__ h,
                                                 const float* __restrict__ dinv,
                                                 const float* __restrict__ bias,
                                                 const int* __restrict__ row_ptr, const int* __restrict__ srcs,
                                                 unsigned short* __restrict__ r1) {
    int g = blockIdx.x * 256 + threadIdx.x;
    int n = g >> 6, lane = g & 63;
    if (n >= N_NODES) return;
    float dn = dinv[n];
    int c = lane * 2;
    unsigned int hv = *(const unsigned int*)(h + (size_t)n * 128 + c);
    float s2 = dn * dn;
    float a0 = fmaf(s2, bf2f((unsigned short)(hv & 0xffffu)), bias[c]);
    float a1 = fmaf(s2, bf2f((unsigned short)(hv >> 16)), bias[c + 1]);
    int e0 = row_ptr[n], e1 = row_ptr[n + 1];
    for (int e = e0; e < e1; e++) {
        int s = srcs[e];
        float nrm = dinv[s] * dn;
        unsigned int hs = *(const unsigned int*)(h + (size_t)s * 128 + c);
        a0 = fmaf(nrm, bf2f((unsigned short)(hs & 0xffffu)), a0);
        a1 = fmaf(nrm, bf2f((unsigned short)(hs >> 16)), a1);
    }
    a0 = fmaxf(a0, 0.0f);
    a1 = fmaxf(a1, 0.0f);
    unsigned int o = (unsigned int)f2bf_rne(a0) | ((unsigned int)f2bf_rne(a1) << 16);
    *(unsigned int*)(r1 + (size_t)n * 128 + c) = o;
}

// ---------------- fused conv2-aggregation + global sum pool ----------------
// P[g][c] = sum_{n in graph g} [ dinv[n]^2*r1[n][c] + sum_e dinv[s]*dinv[n]*r1[s][c] ]
// one block (256 thr) per graph: thread = (col c, node-parity half)
__global__ __launch_bounds__(256) void k_g2pool(const unsigned short* __restrict__ r1,
                                                const float* __restrict__ dinv,
                                                const int* __restrict__ row_ptr, const int* __restrict__ srcs,
                                                const int* __restrict__ gstart,
                                                float* __restrict__ P, int* __restrict__ gcnt) {
    int g = blockIdx.x, t = threadIdx.x;
    int c = t & 127, half = t >> 7;
    int s = gstart[g], e = gstart[g + 1];
    float acc = 0.0f;
    for (int n = s + half; n < e; n += 2) {
        float dn = dinv[n];
        float a = dn * dn * bf2f(r1[(size_t)n * 128 + c]);
        int e0 = row_ptr[n], e1 = row_ptr[n + 1];
        for (int ee = e0; ee < e1; ee++) {
            int sn = srcs[ee];
            a = fmaf(dinv[sn] * dn, bf2f(r1[(size_t)sn * 128 + c]), a);
        }
        acc += a;
    }
    __shared__ float sh[256];
    sh[t] = acc; __syncthreads();
    if (t < 128) P[(size_t)g * 128 + t] = sh[t] + sh[t + 128];
    if (t == 0) gcnt[g] = e - s;
}

// ---------------- zpad build ----------------
__global__ __launch_bounds__(128) void k_zg(const float* __restrict__ P, const int* __restrict__ gcnt,
                                            const float* __restrict__ Wc2, const float* __restrict__ bc2,
                                            const float* __restrict__ solv, float* __restrict__ zpad) {
    int g = blockIdx.x; int c = threadIdx.x;
    if (c >= 80) return;
    float v = 0.0f;
    if (c < 64) {
        const float* pr = P + (size_t)g * 128;
        float s = 0.0f;
        #pragma unroll 8
        for (int k = 0; k < 128; k++) s = fmaf(pr[k], Wc2[k * 64 + c], s);
        v = s + (float)gcnt[g] * bc2[c];
    } else if (c < 75) {
        v = solv[g * 11 + (c - 64)];
    }
    zpad[(size_t)g * 80 + c] = v;
}

// ---------------- W1 pad 75->80 rows ----------------
__global__ __launch_bounds__(256) void k_w1pad(const float* __restrict__ W1, float* __restrict__ w1pad) {
    int i = blockIdx.x * 256 + threadIdx.x;
    if (i >= 80 * 2048) return;
    int r = i / 2048, c = i % 2048;
    w1pad[i] = (r < 75) ? W1[r * 2048 + c] : 0.0f;
}

// ---------------- heads weight concat ----------------
__global__ __launch_bounds__(256) void k_whcat(const float* __restrict__ Wh1, float* __restrict__ whcat) {
    int i = blockIdx.x * 256 + threadIdx.x;
    if (i >= 128 * 256) return;
    int f = i / 256, c = i % 256;
    float v = 0.0f;
    if (c < 192) {
        int h = c / 32, k = c & 31;
        v = Wh1[h * 128 * 32 + f * 32 + k];
    }
    whcat[i] = v;
}
__global__ __launch_bounds__(256) void k_bh1pad(const float* __restrict__ bh1, float* __restrict__ bh1pad) {
    int i = threadIdx.x;
    bh1pad[i] = (i < 192) ? bh1[i] : 0.0f;
}

// ---------------- transpose + hi/lo split ----------------
__global__ __launch_bounds__(256) void k_tsplit(const float* __restrict__ W, int R, int C,
                                                unsigned short* __restrict__ Th, unsigned short* __restrict__ Tl) {
    __shared__ float tile[64][65];
    int cb = blockIdx.x * 64, rb = blockIdx.y * 64;
    int tc = threadIdx.x & 63, tr4 = threadIdx.x >> 6;
    #pragma unroll 4
    for (int i = 0; i < 16; i++) {
        int r = tr4 + i * 4;
        tile[r][tc] = W[(size_t)(rb + r) * C + cb + tc];
    }
    __syncthreads();
    #pragma unroll 4
    for (int i = 0; i < 16; i++) {
        int r = tr4 + i * 4;
        float v = tile[tc][r];
        unsigned short hi, lo; split_bf(v, hi, lo);
        size_t o = (size_t)(cb + r) * R + rb + tc;
        Th[o] = hi; Tl[o] = lo;
    }
}

// ---------------- tiled fp32 GEMM: C = act(A @ B + bias); OMODE 0: fp32, 1: bf16 hi/lo ----------------
template<bool RELU, int OMODE>
__global__ __launch_bounds__(256) void k_gemm(const float* __restrict__ A,
                                              const float* __restrict__ B,
                                              const float* __restrict__ bias,
                                              float* __restrict__ C,
                                              unsigned short* __restrict__ Ch,
                                              unsigned short* __restrict__ Cl,
                                              int M, int N, int K) {
    __shared__ float As[8][132];
    __shared__ float Bs[8][132];
    const int tid = threadIdx.x;
    const int bm = blockIdx.y, bn = blockIdx.x;
    const int tr = (tid >> 4) << 3;
    const int tc = (tid & 15) << 3;
    float acc[8][8] = {};
    const float* Ab = A + (size_t)bm * 128 * K;
    const float* Bb = B + (size_t)bn * 128;
    const int la_r = tid >> 1, la_c = (tid & 1) << 2;
    const int lb_r = tid >> 5, lb_c = (tid & 31) << 2;
    for (int k0 = 0; k0 < K; k0 += 8) {
        float4 a4 = *(const float4*)(Ab + (size_t)la_r * K + k0 + la_c);
        float4 b4 = *(const float4*)(Bb + (size_t)(k0 + lb_r) * N + lb_c);
        __syncthreads();
        As[la_c + 0][la_r] = a4.x;
        As[la_c + 1][la_r] = a4.y;
        As[la_c + 2][la_r] = a4.z;
        As[la_c + 3][la_r] = a4.w;
        *(float4*)&Bs[lb_r][lb_c] = b4;
        __syncthreads();
        #pragma unroll
        for (int k = 0; k < 8; k++) {
            float a[8], b[8];
            *(float4*)&a[0] = *(const float4*)&As[k][tr];
            *(float4*)&a[4] = *(const float4*)&As[k][tr + 4];
            *(float4*)&b[0] = *(const float4*)&Bs[k][tc];
            *(float4*)&b[4] = *(const float4*)&Bs[k][tc + 4];
            #pragma unroll
            for (int i = 0; i < 8; i++)
                #pragma unroll
                for (int j = 0; j < 8; j++)
                    acc[i][j] = fmaf(a[i], b[j], acc[i][j]);
        }
    }
    const int row0 = bm * 128 + tr, col0 = bn * 128 + tc;
    #pragma unroll
    for (int i = 0; i < 8; i++) {
        if (OMODE == 0) {
            #pragma unroll
            for (int j = 0; j < 8; j++) {
                float v = acc[i][j] + bias[col0 + j];
                if (RELU) v = fmaxf(v, 0.0f);
                acc[i][j] = v;
            }
            *(float4*)(C + (size_t)(row0 + i) * N + col0)     = *(float4*)&acc[i][0];
            *(float4*)(C + (size_t)(row0 + i) * N + col0 + 4) = *(float4*)&acc[i][4];
        } else {
            u16x8 h8, l8;
            #pragma unroll
            for (int j = 0; j < 8; j++) {
                float v = acc[i][j] + bias[col0 + j];
                if (RELU) v = fmaxf(v, 0.0f);
                unsigned short hi, lo; split_bf(v, hi, lo);
                h8[j] = hi; l8[j] = lo;
            }
            *(u16x8*)(Ch + (size_t)(row0 + i) * N + col0) = h8;
            *(u16x8*)(Cl + (size_t)(row0 + i) * N + col0) = l8;
        }
    }
}

// ---------------- split-bf16 MFMA GEMM: C[M,N] = relu(A @ B^T + bias) ----------------
template<int OMODE>  // 0: fp32 out, 1: bf16 hi/lo out
__global__ __launch_bounds__(256) void k_mfma_split(
        const unsigned short* __restrict__ Ah, const unsigned short* __restrict__ Al,
        const unsigned short* __restrict__ Bh, const unsigned short* __restrict__ Bl,
        const float* __restrict__ bias,
        float* __restrict__ C, unsigned short* __restrict__ Ch, unsigned short* __restrict__ Cl,
        int N, int K) {
    __shared__ short lds[32768];   // 64 KB: 4 tiles [128 rows][64 bf16], swizzled
    const int tid = threadIdx.x;
    const int w = tid >> 6, l = tid & 63;
    const int id = blockIdx.x;
    const int bm = id & 127;
    const int bn = id >> 7;
    const unsigned short* gmat = (w == 0) ? Ah : (w == 1) ? Al : (w == 2) ? Bh : Bl;
    const size_t grow0 = (size_t)((w < 2) ? bm : bn) * 128 + (l >> 3);
    const int koffg = ((l & 7) ^ ((l >> 3) & 7)) * 8;
    const int ldsw = w * 8192;
    const int wm = w >> 1, wn = w & 1;
    const int lane15 = l & 15, lg = l >> 4, l7 = l & 7;
    f32x4 acc[4][4] = {};
    const int NK = K >> 6;
    for (int kt = 0; kt < NK; kt++) {
        const int k0 = kt << 6;
        __syncthreads();
        #pragma unroll
        for (int i = 0; i < 16; i++) {
            const unsigned short* src = gmat + (grow0 + (size_t)i * 8) * (size_t)K + k0 + koffg;
            __builtin_amdgcn_global_load_lds(
                (const __attribute__((address_space(1))) unsigned int*)src,
                (__attribute__((address_space(3))) unsigned int*)&lds[ldsw + i * 512],
                16, 0, 0);
        }
        __syncthreads();
        #pragma unroll
        for (int kh = 0; kh < 2; kh++) {
            const int slot = ((kh * 4 + lg) ^ l7) * 8;
            bf16x8 ahf[4], alf[4], bhf[4], blf[4];
            #pragma unroll
            for (int m = 0; m < 4; m++) {
                int si = (wm * 64 + m * 16 + lane15) * 64 + slot;
                ahf[m] = *(const bf16x8*)&lds[si];
                alf[m] = *(const bf16x8*)&lds[8192 + si];
            }
            #pragma unroll
            for (int n = 0; n < 4; n++) {
                int si = (wn * 64 + n * 16 + lane15) * 64 + slot;
                bhf[n] = *(const bf16x8*)&lds[16384 + si];
                blf[n] = *(const bf16x8*)&lds[24576 + si];
            }
            #pragma unroll
            for (int m = 0; m < 4; m++)
                #pragma unroll
                for (int n = 0; n < 4; n++) {
                    acc[m][n] = __builtin_amdgcn_mfma_f32_16x16x32_bf16(ahf[m], bhf[n], acc[m][n], 0, 0, 0);
                    acc[m][n] = __builtin_amdgcn_mfma_f32_16x16x32_bf16(ahf[m], blf[n], acc[m][n], 0, 0, 0);
                    acc[m][n] = __builtin_amdgcn_mfma_f32_16x16x32_bf16(alf[m], bhf[n], acc[m][n], 0, 0, 0);
                }
        }
    }
    const int row_b = bm * 128 + wm * 64 + lg * 4;
    const int col_b = bn * 128 + wn * 64 + lane15;
    #pragma unroll
    for (int m = 0; m < 4; m++)
        #pragma unroll
        for (int n = 0; n < 4; n++) {
            int col = col_b + n * 16;
            float bv = bias[col];
            #pragma unroll
            for (int j = 0; j < 4; j++) {
                int row = row_b + m * 16 + j;
                float v = fmaxf(acc[m][n][j] + bv, 0.0f);
                size_t o = (size_t)row * N + col;
                if (OMODE == 0) {
                    C[o] = v;
                } else {
                    unsigned short hi, lo; split_bf(v, hi, lo);
                    Ch[o] = hi; Cl[o] = lo;
                }
            }
        }
}

// ---------------- final heads reduce ----------------
__global__ __launch_bounds__(256) void k_heads_out(const float* __restrict__ a,
                                                   const float* __restrict__ Wh2,
                                                   const float* __restrict__ bh2,
                                                   float* __restrict__ out) {
    int i = blockIdx.x * 256 + threadIdx.x;
    if (i >= N_GRAPHS * 6) return;
    int g = i / 6, h = i % 6;
    const float* ap = a + (size_t)g * 256 + h * 32;
    const float* wp = Wh2 + h * 32;
    float s = 0.0f;
    #pragma unroll
    for (int k = 0; k < 32; k++) s = fmaf(ap[k], wp[k], s);
    out[i] = s + bh2[h];
}

extern "C" void kernel_launch(void* const* d_in, const int* in_sizes, int n_in,
                              void* d_out, int out_size, void* d_ws, size_t ws_size,
                              hipStream_t stream) {
    const float* x    = (const float*)d_in[0];
    const int*   esrc = (const int*)d_in[1];
    const int*   edst = (const int*)d_in[2];
    const int*   batch= (const int*)d_in[3];
    const float* solv = (const float*)d_in[4];
    const float* Wc1  = (const float*)d_in[5];
    const float* bc1  = (const float*)d_in[6];
    const float* Wc2  = (const float*)d_in[7];
    const float* bc2  = (const float*)d_in[8];
    const float* W1   = (const float*)d_in[9];
    const float* b1   = (const float*)d_in[10];
    const float* W2   = (const float*)d_in[11];
    const float* b2   = (const float*)d_in[12];
    const float* W3   = (const float*)d_in[13];
    const float* b3   = (const float*)d_in[14];
    const float* Wh1  = (const float*)d_in[15];
    const float* bh1  = (const float*)d_in[16];
    const float* Wh2  = (const float*)d_in[17];
    const float* bh2  = (const float*)d_in[18];
    float* out = (float*)d_out;

    // workspace layout (floats)
    float* ws    = (float*)d_ws;
    float* bufA  = ws;                             // 64,000,000 f
    float* bufB  = bufA + 64000000;                // 64,000,000 f
    float* dinv  = bufB + 64000000;                // 524,288 f
    float* zpad  = dinv + 524288;                  // 1,310,720 f
    float* w1pad = zpad + (size_t)N_GRAPHS * 80;   // 163,840 f
    float* whcat = w1pad + 80 * 2048;              // 32,768 f
    float* bh1p  = whcat + 128 * 256;              // 256 f
    int* counts  = (int*)(bh1p + 256);             // 500,000
    int* row_ptr = counts + N_NODES;               // 500,224
    int* cursor  = row_ptr + 500224;               // 500,000
    int* srcs    = cursor + N_NODES;               // 2,000,000
    int* bsum    = srcs + N_EDGES;                 // 256
    int* boff    = bsum + 256;                     // 256
    int* gstart  = boff + 256;                     // 16,640
    int* gcnt    = gstart + 16640;                 // 16,384
    float* P     = bufB + 61902848;                // 2,097,152 f (tail of bufB)

    // bf16 conv activations
    unsigned short* h_bf = (unsigned short*)bufA;  // [500k,128] u16 = 32M f
    unsigned short* r1   = (unsigned short*)bufB;  // [500k,128] u16 = 32M f

    // hi/lo activations & weights (timeline-disjoint reuse)
    unsigned short* z1h = (unsigned short*)bufB;                // after r1 dead
    unsigned short* z1l = (unsigned short*)(bufB + 16800000);
    unsigned short* z2h = (unsigned short*)bufA;                // after h_bf dead
    unsigned short* z2l = (unsigned short*)(bufA + 8400000);
    float* z3 = bufB + 34000000;
    unsigned short* w2th = (unsigned short*)(bufA + 17000000);  // written after h_bf dead
    unsigned short* w2tl = (unsigned short*)(bufA + 18100000);
    unsigned short* w3th = (unsigned short*)(bufA + 19200000);
    unsigned short* w3tl = (unsigned short*)(bufA + 19300000);
    float* ab = bufA + 20000000;

    // 1) CSR build + dinv + graph segments
    k_zero_counts<<<(N_NODES + 255) / 256, 256, 0, stream>>>(counts);
    k_hist<<<(N_EDGES + 255) / 256, 256, 0, stream>>>(edst, counts);
    k_scan_reduce<<<SCAN_NBLK, 256, 0, stream>>>(counts, bsum);
    k_scan_bsum<<<1, 256, 0, stream>>>(bsum, boff, row_ptr);
    k_scan_final<<<SCAN_NBLK, 256, 0, stream>>>(counts, boff, row_ptr, cursor, dinv);
    k_fill<<<(N_EDGES + 255) / 256, 256, 0, stream>>>(esrc, edst, cursor, srcs);
    k_gstart<<<(N_GRAPHS + 256) / 256, 256, 0, stream>>>(batch, gstart);

    // 2) conv1: h_bf = bf16(x @ Wc1) ; gather+relu -> r1 (bf16)
    k_gemm_conv1<131><<<(N_NODES + 127) / 128, 256, 0, stream>>>(x, Wc1, h_bf, N_NODES);
    k_gather1<<<(N_NODES * 64) / 256, 256, 0, stream>>>(h_bf, dinv, bc1, row_ptr, srcs, r1);

    // 3) fused conv2-agg + pool -> P ; then zpad
    k_g2pool<<<N_GRAPHS, 256, 0, stream>>>(r1, dinv, row_ptr, srcs, gstart, P, gcnt);

    // weight transposes+splits (h_bf region free after gather1; runs after g2pool issued)
    k_tsplit<<<dim3(1024 / 64, 2048 / 64), 256, 0, stream>>>(W2, 2048, 1024, w2th, w2tl);
    k_tsplit<<<dim3(128 / 64, 1024 / 64), 256, 0, stream>>>(W3, 1024, 128, w3th, w3tl);

    k_zg<<<N_GRAPHS, 128, 0, stream>>>(P, gcnt, Wc2, bc2, solv, zpad);

    // 4) MLP
    k_w1pad<<<(80 * 2048) / 256, 256, 0, stream>>>(W1, w1pad);
    k_whcat<<<(128 * 256) / 256, 256, 0, stream>>>(Wh1, whcat);
    k_bh1pad<<<1, 256, 0, stream>>>(bh1, bh1p);

    // W1 (fp32, K=80) -> z1 hi/lo
    k_gemm<true, 1><<<dim3(2048 / 128, N_GRAPHS / 128), 256, 0, stream>>>(
        zpad, w1pad, b1, nullptr, z1h, z1l, N_GRAPHS, 2048, 80);
    // W2 (split-bf16 MFMA, K=2048) -> z2 hi/lo
    k_mfma_split<1><<<(1024 / 128) * (N_GRAPHS / 128), 256, 0, stream>>>(
        z1h, z1l, w2th, w2tl, b2, nullptr, z2h, z2l, 1024, 2048);
    // W3 (split-bf16 MFMA, K=1024) -> z3 fp32
    k_mfma_split<0><<<(128 / 128) * (N_GRAPHS / 128), 256, 0, stream>>>(
        z2h, z2l, w3th, w3tl, b3, z3, nullptr, nullptr, 128, 1024);

    // 5) heads (fp32, K=128)
    k_gemm<true, 0><<<dim3(256 / 128, N_GRAPHS / 128), 256, 0, stream>>>(
        z3, whcat, bh1p, ab, nullptr, nullptr, N_GRAPHS, 256, 128);
    k_heads_out<<<(N_GRAPHS * 6 + 255) / 256, 256, 0, stream>>>(ab, Wh2, bh2, out);
}

// Round 6
// 1251.378 us; speedup vs baseline: 1.3509x; 1.3509x over previous
//
#include <hip/hip_runtime.h>

#define N_NODES 500000
#define N_EDGES 2000000
#define N_GRAPHS 16384
#define STRIP 16

#define SCAN_ELEMS 2048
#define SCAN_NBLK ((N_NODES + SCAN_ELEMS - 1) / SCAN_ELEMS)   // 245

typedef short bf16x8 __attribute__((ext_vector_type(8)));
typedef float f32x4 __attribute__((ext_vector_type(4)));
typedef unsigned short u16x8 __attribute__((ext_vector_type(8)));

__device__ __forceinline__ unsigned short f2bf_rne(float x) {
    unsigned int b = __float_as_uint(x);
    unsigned int r = (b + 0x7fffu + ((b >> 16) & 1u)) >> 16;
    return (unsigned short)r;
}
__device__ __forceinline__ float bf2f(unsigned short h) {
    return __uint_as_float(((unsigned int)h) << 16);
}
__device__ __forceinline__ void split_bf(float v, unsigned short& hi, unsigned short& lo) {
    hi = f2bf_rne(v);
    lo = f2bf_rne(v - bf2f(hi));
}

// ---------------- CSR build ----------------
__global__ __launch_bounds__(256) void k_zero_counts(int* counts) {
    int i = blockIdx.x * 256 + threadIdx.x;
    if (i < N_NODES) counts[i] = 0;
}
__global__ __launch_bounds__(256) void k_hist(const int* __restrict__ dst, int* __restrict__ counts) {
    int e = blockIdx.x * 256 + threadIdx.x;
    if (e < N_EDGES) atomicAdd(&counts[dst[e]], 1);
}
__global__ __launch_bounds__(256) void k_scan_reduce(const int* __restrict__ counts, int* __restrict__ bsum) {
    int b = blockIdx.x, t = threadIdx.x;
    int base_i = b * SCAN_ELEMS + t * 8;
    int s = 0;
    #pragma unroll
    for (int j = 0; j < 8; j++) { int i = base_i + j; if (i < N_NODES) s += counts[i]; }
    __shared__ int sh[256];
    sh[t] = s; __syncthreads();
    for (int off = 128; off > 0; off >>= 1) { if (t < off) sh[t] += sh[t + off]; __syncthreads(); }
    if (t == 0) bsum[b] = sh[0];
}
__global__ __launch_bounds__(256) void k_scan_bsum(const int* __restrict__ bsum, int* __restrict__ boff,
                                                   int* __restrict__ row_ptr) {
    __shared__ int sh[256];
    int t = threadIdx.x;
    int v = (t < SCAN_NBLK) ? bsum[t] : 0;
    sh[t] = v; __syncthreads();
    for (int off = 1; off < 256; off <<= 1) {
        int u = (t >= off) ? sh[t - off] : 0;
        __syncthreads();
        sh[t] += u; __syncthreads();
    }
    boff[t] = sh[t] - v;
    if (t == 255) row_ptr[N_NODES] = sh[255];
}
__global__ __launch_bounds__(256) void k_scan_final(const int* __restrict__ counts, const int* __restrict__ boff,
                                                    int* __restrict__ row_ptr, int* __restrict__ cursor,
                                                    float* __restrict__ dinv) {
    __shared__ int sh[256];
    int b = blockIdx.x, t = threadIdx.x;
    int base_i = b * SCAN_ELEMS + t * 8;
    int c[8]; int tsum = 0;
    #pragma unroll
    for (int j = 0; j < 8; j++) {
        int i = base_i + j;
        c[j] = (i < N_NODES) ? counts[i] : 0;
        tsum += c[j];
    }
    sh[t] = tsum; __syncthreads();
    for (int off = 1; off < 256; off <<= 1) {
        int u = (t >= off) ? sh[t - off] : 0;
        __syncthreads();
        sh[t] += u; __syncthreads();
    }
    int run = boff[b] + sh[t] - tsum;
    #pragma unroll
    for (int j = 0; j < 8; j++) {
        int i = base_i + j;
        if (i < N_NODES) {
            row_ptr[i] = run;
            cursor[i]  = run;
            dinv[i]    = rsqrtf((float)c[j] + 1.0f);
        }
        run += c[j];
    }
}
__global__ __launch_bounds__(256) void k_fill(const int* __restrict__ esrc, const int* __restrict__ edst,
                                              int* __restrict__ cursor, int* __restrict__ srcs) {
    int e = blockIdx.x * 256 + threadIdx.x;
    if (e >= N_EDGES) return;
    int d = edst[e];
    int pos = atomicAdd(&cursor[d], 1);
    srcs[pos] = esrc[e];
}
__global__ __launch_bounds__(256) void k_gstart(const int* __restrict__ batch, int* __restrict__ gstart) {
    int g = blockIdx.x * 256 + threadIdx.x;
    if (g > N_GRAPHS) return;
    if (g == N_GRAPHS) { gstart[g] = N_NODES; return; }
    int lo = 0, hi = N_NODES;
    while (lo < hi) { int mid = (lo + hi) >> 1; if (batch[mid] < g) lo = mid + 1; else hi = mid; }
    gstart[g] = lo;
}
__global__ __launch_bounds__(256) void k_zero_P(float* P) {
    int i = blockIdx.x * 256 + threadIdx.x;
    if (i < N_GRAPHS * 128) P[i] = 0.0f;
}

// ---------------- conv1 tiled GEMM: C[M,128] = bf16(A[M,131] @ B[131,128]) ----------------
template<int KTOT>
__global__ __launch_bounds__(256) void k_gemm_conv1(const float* __restrict__ A,
                                                    const float* __restrict__ B,
                                                    unsigned short* __restrict__ C, int Mreal) {
    __shared__ float As[8][132];
    __shared__ float Bs[8][132];
    const int tid = threadIdx.x;
    const int bm = blockIdx.x;
    const int tr = (tid >> 4) << 3;
    const int tc = (tid & 15) << 3;
    float acc[8][8] = {};
    const int la_r = tid >> 1, la_c = (tid & 1) << 2;
    const int lb_r = tid >> 5, lb_c = (tid & 31) << 2;
    const int arow = min(bm * 128 + la_r, Mreal - 1);
    const float* Ap = A + (size_t)arow * KTOT + la_c;
    constexpr int KMAIN = (KTOT / 8) * 8;
    for (int k0 = 0; k0 < KMAIN; k0 += 8) {
        float4 a4 = *(const float4*)(Ap + k0);
        float4 b4 = *(const float4*)(B + (size_t)(k0 + lb_r) * 128 + lb_c);
        __syncthreads();
        As[la_c + 0][la_r] = a4.x;
        As[la_c + 1][la_r] = a4.y;
        As[la_c + 2][la_r] = a4.z;
        As[la_c + 3][la_r] = a4.w;
        *(float4*)&Bs[lb_r][lb_c] = b4;
        __syncthreads();
        #pragma unroll
        for (int k = 0; k < 8; k++) {
            float a[8], b[8];
            *(float4*)&a[0] = *(const float4*)&As[k][tr];
            *(float4*)&a[4] = *(const float4*)&As[k][tr + 4];
            *(float4*)&b[0] = *(const float4*)&Bs[k][tc];
            *(float4*)&b[4] = *(const float4*)&Bs[k][tc + 4];
            #pragma unroll
            for (int i = 0; i < 8; i++)
                #pragma unroll
                for (int j = 0; j < 8; j++)
                    acc[i][j] = fmaf(a[i], b[j], acc[i][j]);
        }
    }
    if (KTOT % 8 != 0) {
        constexpr int k0 = KMAIN;
        float av[4];
        #pragma unroll
        for (int j = 0; j < 4; j++) av[j] = (k0 + la_c + j < KTOT) ? Ap[k0 + j] : 0.0f;
        float4 b4 = {0.f, 0.f, 0.f, 0.f};
        if (k0 + lb_r < KTOT) b4 = *(const float4*)(B + (size_t)(k0 + lb_r) * 128 + lb_c);
        __syncthreads();
        As[la_c + 0][la_r] = av[0];
        As[la_c + 1][la_r] = av[1];
        As[la_c + 2][la_r] = av[2];
        As[la_c + 3][la_r] = av[3];
        *(float4*)&Bs[lb_r][lb_c] = b4;
        __syncthreads();
        #pragma unroll
        for (int k = 0; k < 8; k++) {
            float a[8], b[8];
            *(float4*)&a[0] = *(const float4*)&As[k][tr];
            *(float4*)&a[4] = *(const float4*)&As[k][tr + 4];
            *(float4*)&b[0] = *(const float4*)&Bs[k][tc];
            *(float4*)&b[4] = *(const float4*)&Bs[k][tc + 4];
            #pragma unroll
            for (int i = 0; i < 8; i++)
                #pragma unroll
                for (int j = 0; j < 8; j++)
                    acc[i][j] = fmaf(a[i], b[j], acc[i][j]);
        }
    }
    const int row0 = bm * 128 + tr;
    #pragma unroll
    for (int i = 0; i < 8; i++) {
        if (row0 + i < Mreal) {
            u16x8 o;
            #pragma unroll
            for (int j = 0; j < 8; j++) o[j] = f2bf_rne(acc[i][j]);
            *(u16x8*)(C + (size_t)(row0 + i) * 128 + tc) = o;
        }
    }
}

// ---------------- conv1 gather (bf16 in, fp32 accum, relu, bf16 out), edge loop x2 ----------------
__global__ __launch_bounds__(256) void k_gather1(const unsigned short* __restrict__ h,
                                                 const float* __restrict__ dinv,
                                                 const float* __restrict__ bias,
                                                 const int* __restrict__ row_ptr, const int* __restrict__ srcs,
                                                 unsigned short* __restrict__ r1) {
    int g = blockIdx.x * 256 + threadIdx.x;
    int n = g >> 6, lane = g & 63;
    if (n >= N_NODES) return;
    float dn = dinv[n];
    int c = lane * 2;
    unsigned int hv = *(const unsigned int*)(h + (size_t)n * 128 + c);
    float s2 = dn * dn;
    float a0 = fmaf(s2, bf2f((unsigned short)(hv & 0xffffu)), bias[c]);
    float a1 = fmaf(s2, bf2f((unsigned short)(hv >> 16)), bias[c + 1]);
    int e0 = row_ptr[n], e1 = row_ptr[n + 1];
    int e = e0;
    for (; e + 2 <= e1; e += 2) {
        int sA = srcs[e], sB = srcs[e + 1];
        float nA = dinv[sA] * dn, nB = dinv[sB] * dn;
        unsigned int hA = *(const unsigned int*)(h + (size_t)sA * 128 + c);
        unsigned int hB = *(const unsigned int*)(h + (size_t)sB * 128 + c);
        a0 = fmaf(nA, bf2f((unsigned short)(hA & 0xffffu)), a0);
        a1 = fmaf(nA, bf2f((unsigned short)(hA >> 16)), a1);
        a0 = fmaf(nB, bf2f((unsigned short)(hB & 0xffffu)), a0);
        a1 = fmaf(nB, bf2f((unsigned short)(hB >> 16)), a1);
    }
    if (e < e1) {
        int sA = srcs[e];
        float nA = dinv[sA] * dn;
        unsigned int hA = *(const unsigned int*)(h + (size_t)sA * 128 + c);
        a0 = fmaf(nA, bf2f((unsigned short)(hA & 0xffffu)), a0);
        a1 = fmaf(nA, bf2f((unsigned short)(hA >> 16)), a1);
    }
    a0 = fmaxf(a0, 0.0f);
    a1 = fmaxf(a1, 0.0f);
    unsigned int o = (unsigned int)f2bf_rne(a0) | ((unsigned int)f2bf_rne(a1) << 16);
    *(unsigned int*)(r1 + (size_t)n * 128 + c) = o;
}

// ---------------- fused conv2-agg + pool: wave-per-16-node strip, register segment-sum, atomic flush ----------------
// P[g][c] += sum_{n in strip, batch[n]=g} [ dinv[n]^2*r1[n][c] + sum_e dinv[s]*dinv[n]*r1[s][c] ]
__global__ __launch_bounds__(256) void k_g2p(const unsigned short* __restrict__ r1,
                                             const float* __restrict__ dinv,
                                             const int* __restrict__ row_ptr, const int* __restrict__ srcs,
                                             const int* __restrict__ batch,
                                             float* __restrict__ P) {
    int gw = (blockIdx.x * 256 + threadIdx.x) >> 6;
    int lane = threadIdx.x & 63;
    if (gw >= N_NODES / STRIP) return;
    int n0 = gw * STRIP;
    int c = lane * 2;
    float a0 = 0.0f, a1 = 0.0f;
    int cur_g = batch[n0];
    for (int n = n0; n < n0 + STRIP; n++) {
        int bg = batch[n];
        if (bg != cur_g) {
            atomicAdd(&P[(size_t)cur_g * 128 + c], a0);
            atomicAdd(&P[(size_t)cur_g * 128 + c + 1], a1);
            a0 = a1 = 0.0f;
            cur_g = bg;
        }
        float dn = dinv[n];
        float s2 = dn * dn;
        unsigned int hv = *(const unsigned int*)(r1 + (size_t)n * 128 + c);
        a0 = fmaf(s2, bf2f((unsigned short)(hv & 0xffffu)), a0);
        a1 = fmaf(s2, bf2f((unsigned short)(hv >> 16)), a1);
        int e0 = row_ptr[n], e1 = row_ptr[n + 1];
        int e = e0;
        for (; e + 2 <= e1; e += 2) {
            int sA = srcs[e], sB = srcs[e + 1];
            float nA = dinv[sA] * dn, nB = dinv[sB] * dn;
            unsigned int hA = *(const unsigned int*)(r1 + (size_t)sA * 128 + c);
            unsigned int hB = *(const unsigned int*)(r1 + (size_t)sB * 128 + c);
            a0 = fmaf(nA, bf2f((unsigned short)(hA & 0xffffu)), a0);
            a1 = fmaf(nA, bf2f((unsigned short)(hA >> 16)), a1);
            a0 = fmaf(nB, bf2f((unsigned short)(hB & 0xffffu)), a0);
            a1 = fmaf(nB, bf2f((unsigned short)(hB >> 16)), a1);
        }
        if (e < e1) {
            int sA = srcs[e];
            float nA = dinv[sA] * dn;
            unsigned int hA = *(const unsigned int*)(r1 + (size_t)sA * 128 + c);
            a0 = fmaf(nA, bf2f((unsigned short)(hA & 0xffffu)), a0);
            a1 = fmaf(nA, bf2f((unsigned short)(hA >> 16)), a1);
        }
    }
    atomicAdd(&P[(size_t)cur_g * 128 + c], a0);
    atomicAdd(&P[(size_t)cur_g * 128 + c + 1], a1);
}

// ---------------- zpad build: cols 0..63 = P@Wc2 + cnt*bc2 ; 64..74 = solv ; 75..79 = 0 ----------------
__global__ __launch_bounds__(128) void k_zg(const float* __restrict__ P, const int* __restrict__ gstart,
                                            const float* __restrict__ Wc2, const float* __restrict__ bc2,
                                            const float* __restrict__ solv, float* __restrict__ zpad) {
    int g = blockIdx.x; int c = threadIdx.x;
    if (c >= 80) return;
    float v = 0.0f;
    if (c < 64) {
        const float* pr = P + (size_t)g * 128;
        float s = 0.0f;
        #pragma unroll 8
        for (int k = 0; k < 128; k++) s = fmaf(pr[k], Wc2[k * 64 + c], s);
        v = s + (float)(gstart[g + 1] - gstart[g]) * bc2[c];
    } else if (c < 75) {
        v = solv[g * 11 + (c - 64)];
    }
    zpad[(size_t)g * 80 + c] = v;
}

// ---------------- W1 pad 75->80 rows ----------------
__global__ __launch_bounds__(256) void k_w1pad(const float* __restrict__ W1, float* __restrict__ w1pad) {
    int i = blockIdx.x * 256 + threadIdx.x;
    if (i >= 80 * 2048) return;
    int r = i / 2048, c = i % 2048;
    w1pad[i] = (r < 75) ? W1[r * 2048 + c] : 0.0f;
}

// ---------------- heads weight concat ----------------
__global__ __launch_bounds__(256) void k_whcat(const float* __restrict__ Wh1, float* __restrict__ whcat) {
    int i = blockIdx.x * 256 + threadIdx.x;
    if (i >= 128 * 256) return;
    int f = i / 256, c = i % 256;
    float v = 0.0f;
    if (c < 192) {
        int h = c / 32, k = c & 31;
        v = Wh1[h * 128 * 32 + f * 32 + k];
    }
    whcat[i] = v;
}
__global__ __launch_bounds__(256) void k_bh1pad(const float* __restrict__ bh1, float* __restrict__ bh1pad) {
    int i = threadIdx.x;
    bh1pad[i] = (i < 192) ? bh1[i] : 0.0f;
}

// ---------------- transpose + hi/lo split ----------------
__global__ __launch_bounds__(256) void k_tsplit(const float* __restrict__ W, int R, int C,
                                                unsigned short* __restrict__ Th, unsigned short* __restrict__ Tl) {
    __shared__ float tile[64][65];
    int cb = blockIdx.x * 64, rb = blockIdx.y * 64;
    int tc = threadIdx.x & 63, tr4 = threadIdx.x >> 6;
    #pragma unroll 4
    for (int i = 0; i < 16; i++) {
        int r = tr4 + i * 4;
        tile[r][tc] = W[(size_t)(rb + r) * C + cb + tc];
    }
    __syncthreads();
    #pragma unroll 4
    for (int i = 0; i < 16; i++) {
        int r = tr4 + i * 4;
        float v = tile[tc][r];
        unsigned short hi, lo; split_bf(v, hi, lo);
        size_t o = (size_t)(cb + r) * R + rb + tc;
        Th[o] = hi; Tl[o] = lo;
    }
}

// ---------------- tiled fp32 GEMM: C = act(A @ B + bias); OMODE 0: fp32, 1: bf16 hi/lo ----------------
template<bool RELU, int OMODE>
__global__ __launch_bounds__(256) void k_gemm(const float* __restrict__ A,
                                              const float* __restrict__ B,
                                              const float* __restrict__ bias,
                                              float* __restrict__ C,
                                              unsigned short* __restrict__ Ch,
                                              unsigned short* __restrict__ Cl,
                                              int M, int N, int K) {
    __shared__ float As[8][132];
    __shared__ float Bs[8][132];
    const int tid = threadIdx.x;
    const int bm = blockIdx.y, bn = blockIdx.x;
    const int tr = (tid >> 4) << 3;
    const int tc = (tid & 15) << 3;
    float acc[8][8] = {};
    const float* Ab = A + (size_t)bm * 128 * K;
    const float* Bb = B + (size_t)bn * 128;
    const int la_r = tid >> 1, la_c = (tid & 1) << 2;
    const int lb_r = tid >> 5, lb_c = (tid & 31) << 2;
    for (int k0 = 0; k0 < K; k0 += 8) {
        float4 a4 = *(const float4*)(Ab + (size_t)la_r * K + k0 + la_c);
        float4 b4 = *(const float4*)(Bb + (size_t)(k0 + lb_r) * N + lb_c);
        __syncthreads();
        As[la_c + 0][la_r] = a4.x;
        As[la_c + 1][la_r] = a4.y;
        As[la_c + 2][la_r] = a4.z;
        As[la_c + 3][la_r] = a4.w;
        *(float4*)&Bs[lb_r][lb_c] = b4;
        __syncthreads();
        #pragma unroll
        for (int k = 0; k < 8; k++) {
            float a[8], b[8];
            *(float4*)&a[0] = *(const float4*)&As[k][tr];
            *(float4*)&a[4] = *(const float4*)&As[k][tr + 4];
            *(float4*)&b[0] = *(const float4*)&Bs[k][tc];
            *(float4*)&b[4] = *(const float4*)&Bs[k][tc + 4];
            #pragma unroll
            for (int i = 0; i < 8; i++)
                #pragma unroll
                for (int j = 0; j < 8; j++)
                    acc[i][j] = fmaf(a[i], b[j], acc[i][j]);
        }
    }
    const int row0 = bm * 128 + tr, col0 = bn * 128 + tc;
    #pragma unroll
    for (int i = 0; i < 8; i++) {
        if (OMODE == 0) {
            #pragma unroll
            for (int j = 0; j < 8; j++) {
                float v = acc[i][j] + bias[col0 + j];
                if (RELU) v = fmaxf(v, 0.0f);
                acc[i][j] = v;
            }
            *(float4*)(C + (size_t)(row0 + i) * N + col0)     = *(float4*)&acc[i][0];
            *(float4*)(C + (size_t)(row0 + i) * N + col0 + 4) = *(float4*)&acc[i][4];
        } else {
            u16x8 h8, l8;
            #pragma unroll
            for (int j = 0; j < 8; j++) {
                float v = acc[i][j] + bias[col0 + j];
                if (RELU) v = fmaxf(v, 0.0f);
                unsigned short hi, lo; split_bf(v, hi, lo);
                h8[j] = hi; l8[j] = lo;
            }
            *(u16x8*)(Ch + (size_t)(row0 + i) * N + col0) = h8;
            *(u16x8*)(Cl + (size_t)(row0 + i) * N + col0) = l8;
        }
    }
}

// ---------------- split-bf16 MFMA GEMM: C[M,N] = relu(A @ B^T + bias) ----------------
template<int OMODE>  // 0: fp32 out, 1: bf16 hi/lo out
__global__ __launch_bounds__(256) void k_mfma_split(
        const unsigned short* __restrict__ Ah, const unsigned short* __restrict__ Al,
        const unsigned short* __restrict__ Bh, const unsigned short* __restrict__ Bl,
        const float* __restrict__ bias,
        float* __restrict__ C, unsigned short* __restrict__ Ch, unsigned short* __restrict__ Cl,
        int N, int K) {
    __shared__ short lds[32768];   // 64 KB: 4 tiles [128 rows][64 bf16], swizzled
    const int tid = threadIdx.x;
    const int w = tid >> 6, l = tid & 63;
    const int id = blockIdx.x;
    const int bm = id & 127;
    const int bn = id >> 7;
    const unsigned short* gmat = (w == 0) ? Ah : (w == 1) ? Al : (w == 2) ? Bh : Bl;
    const size_t grow0 = (size_t)((w < 2) ? bm : bn) * 128 + (l >> 3);
    const int koffg = ((l & 7) ^ ((l >> 3) & 7)) * 8;
    const int ldsw = w * 8192;
    const int wm = w >> 1, wn = w & 1;
    const int lane15 = l & 15, lg = l >> 4, l7 = l & 7;
    f32x4 acc[4][4] = {};
    const int NK = K >> 6;
    for (int kt = 0; kt < NK; kt++) {
        const int k0 = kt << 6;
        __syncthreads();
        #pragma unroll
        for (int i = 0; i < 16; i++) {
            const unsigned short* src = gmat + (grow0 + (size_t)i * 8) * (size_t)K + k0 + koffg;
            __builtin_amdgcn_global_load_lds(
                (const __attribute__((address_space(1))) unsigned int*)src,
                (__attribute__((address_space(3))) unsigned int*)&lds[ldsw + i * 512],
                16, 0, 0);
        }
        __syncthreads();
        #pragma unroll
        for (int kh = 0; kh < 2; kh++) {
            const int slot = ((kh * 4 + lg) ^ l7) * 8;
            bf16x8 ahf[4], alf[4], bhf[4], blf[4];
            #pragma unroll
            for (int m = 0; m < 4; m++) {
                int si = (wm * 64 + m * 16 + lane15) * 64 + slot;
                ahf[m] = *(const bf16x8*)&lds[si];
                alf[m] = *(const bf16x8*)&lds[8192 + si];
            }
            #pragma unroll
            for (int n = 0; n < 4; n++) {
                int si = (wn * 64 + n * 16 + lane15) * 64 + slot;
                bhf[n] = *(const bf16x8*)&lds[16384 + si];
                blf[n] = *(const bf16x8*)&lds[24576 + si];
            }
            #pragma unroll
            for (int m = 0; m < 4; m++)
                #pragma unroll
                for (int n = 0; n < 4; n++) {
                    acc[m][n] = __builtin_amdgcn_mfma_f32_16x16x32_bf16(ahf[m], bhf[n], acc[m][n], 0, 0, 0);
                    acc[m][n] = __builtin_amdgcn_mfma_f32_16x16x32_bf16(ahf[m], blf[n], acc[m][n], 0, 0, 0);
                    acc[m][n] = __builtin_amdgcn_mfma_f32_16x16x32_bf16(alf[m], bhf[n], acc[m][n], 0, 0, 0);
                }
        }
    }
    const int row_b = bm * 128 + wm * 64 + lg * 4;
    const int col_b = bn * 128 + wn * 64 + lane15;
    #pragma unroll
    for (int m = 0; m < 4; m++)
        #pragma unroll
        for (int n = 0; n < 4; n++) {
            int col = col_b + n * 16;
            float bv = bias[col];
            #pragma unroll
            for (int j = 0; j < 4; j++) {
                int row = row_b + m * 16 + j;
                float v = fmaxf(acc[m][n][j] + bv, 0.0f);
                size_t o = (size_t)row * N + col;
                if (OMODE == 0) {
                    C[o] = v;
                } else {
                    unsigned short hi, lo; split_bf(v, hi, lo);
                    Ch[o] = hi; Cl[o] = lo;
                }
            }
        }
}

// ---------------- final heads reduce ----------------
__global__ __launch_bounds__(256) void k_heads_out(const float* __restrict__ a,
                                                   const float* __restrict__ Wh2,
                                                   const float* __restrict__ bh2,
                                                   float* __restrict__ out) {
    int i = blockIdx.x * 256 + threadIdx.x;
    if (i >= N_GRAPHS * 6) return;
    int g = i / 6, h = i % 6;
    const float* ap = a + (size_t)g * 256 + h * 32;
    const float* wp = Wh2 + h * 32;
    float s = 0.0f;
    #pragma unroll
    for (int k = 0; k < 32; k++) s = fmaf(ap[k], wp[k], s);
    out[i] = s + bh2[h];
}

extern "C" void kernel_launch(void* const* d_in, const int* in_sizes, int n_in,
                              void* d_out, int out_size, void* d_ws, size_t ws_size,
                              hipStream_t stream) {
    const float* x    = (const float*)d_in[0];
    const int*   esrc = (const int*)d_in[1];
    const int*   edst = (const int*)d_in[2];
    const int*   batch= (const int*)d_in[3];
    const float* solv = (const float*)d_in[4];
    const float* Wc1  = (const float*)d_in[5];
    const float* bc1  = (const float*)d_in[6];
    const float* Wc2  = (const float*)d_in[7];
    const float* bc2  = (const float*)d_in[8];
    const float* W1   = (const float*)d_in[9];
    const float* b1   = (const float*)d_in[10];
    const float* W2   = (const float*)d_in[11];
    const float* b2   = (const float*)d_in[12];
    const float* W3   = (const float*)d_in[13];
    const float* b3   = (const float*)d_in[14];
    const float* Wh1  = (const float*)d_in[15];
    const float* bh1  = (const float*)d_in[16];
    const float* Wh2  = (const float*)d_in[17];
    const float* bh2  = (const float*)d_in[18];
    float* out = (float*)d_out;

    // workspace layout (floats)
    float* ws    = (float*)d_ws;
    float* bufA  = ws;                             // 64,000,000 f
    float* bufB  = bufA + 64000000;                // 64,000,000 f
    float* dinv  = bufB + 64000000;                // 524,288 f
    float* zpad  = dinv + 524288;                  // 1,310,720 f
    float* w1pad = zpad + (size_t)N_GRAPHS * 80;   // 163,840 f
    float* whcat = w1pad + 80 * 2048;              // 32,768 f
    float* bh1p  = whcat + 128 * 256;              // 256 f
    int* counts  = (int*)(bh1p + 256);             // 500,000
    int* row_ptr = counts + N_NODES;               // 500,224
    int* cursor  = row_ptr + 500224;               // 500,000
    int* srcs    = cursor + N_NODES;               // 2,000,000
    int* bsum    = srcs + N_EDGES;                 // 256
    int* boff    = bsum + 256;                     // 256
    int* gstart  = boff + 256;                     // 16,640
    float* P     = bufB + 61902848;                // 2,097,152 f (tail of bufB)

    // bf16 conv activations
    unsigned short* h_bf = (unsigned short*)bufA;  // [500k,128] u16 (bufA[0:32M f))
    unsigned short* r1   = (unsigned short*)bufB;  // [500k,128] u16 (bufB[0:32M f))

    // hi/lo activations & weights (timeline-disjoint reuse)
    unsigned short* z1h = (unsigned short*)bufB;                // after r1 dead
    unsigned short* z1l = (unsigned short*)(bufB + 16800000);
    unsigned short* z2h = (unsigned short*)bufA;                // after h_bf dead
    unsigned short* z2l = (unsigned short*)(bufA + 8400000);
    float* z3 = bufB + 34000000;
    unsigned short* w2th = (unsigned short*)(bufA + 33000000);  // written after h_bf dead
    unsigned short* w2tl = (unsigned short*)(bufA + 34100000);
    unsigned short* w3th = (unsigned short*)(bufA + 35200000);
    unsigned short* w3tl = (unsigned short*)(bufA + 35300000);
    float* ab = bufA + 36000000;

    // 1) CSR build + dinv + graph segments + P zero
    k_zero_counts<<<(N_NODES + 255) / 256, 256, 0, stream>>>(counts);
    k_hist<<<(N_EDGES + 255) / 256, 256, 0, stream>>>(edst, counts);
    k_scan_reduce<<<SCAN_NBLK, 256, 0, stream>>>(counts, bsum);
    k_scan_bsum<<<1, 256, 0, stream>>>(bsum, boff, row_ptr);
    k_scan_final<<<SCAN_NBLK, 256, 0, stream>>>(counts, boff, row_ptr, cursor, dinv);
    k_fill<<<(N_EDGES + 255) / 256, 256, 0, stream>>>(esrc, edst, cursor, srcs);
    k_gstart<<<(N_GRAPHS + 256) / 256, 256, 0, stream>>>(batch, gstart);
    k_zero_P<<<(N_GRAPHS * 128) / 256, 256, 0, stream>>>(P);

    // 2) conv1: h_bf = bf16(x @ Wc1) ; gather+relu -> r1 (bf16)
    k_gemm_conv1<131><<<(N_NODES + 127) / 128, 256, 0, stream>>>(x, Wc1, h_bf, N_NODES);
    k_gather1<<<(N_NODES * 64) / 256, 256, 0, stream>>>(h_bf, dinv, bc1, row_ptr, srcs, r1);

    // 3) fused conv2-agg + pool -> P (strip waves, register segment-sum, atomic flush)
    k_g2p<<<((N_NODES / STRIP) * 64 + 255) / 256, 256, 0, stream>>>(r1, dinv, row_ptr, srcs, batch, P);

    // weight transposes+splits (after g2p in stream order; region disjoint from live data)
    k_tsplit<<<dim3(1024 / 64, 2048 / 64), 256, 0, stream>>>(W2, 2048, 1024, w2th, w2tl);
    k_tsplit<<<dim3(128 / 64, 1024 / 64), 256, 0, stream>>>(W3, 1024, 128, w3th, w3tl);

    k_zg<<<N_GRAPHS, 128, 0, stream>>>(P, gstart, Wc2, bc2, solv, zpad);

    // 4) MLP
    k_w1pad<<<(80 * 2048) / 256, 256, 0, stream>>>(W1, w1pad);
    k_whcat<<<(128 * 256) / 256, 256, 0, stream>>>(Wh1, whcat);
    k_bh1pad<<<1, 256, 0, stream>>>(bh1, bh1p);

    // W1 (fp32, K=80) -> z1 hi/lo
    k_gemm<true, 1><<<dim3(2048 / 128, N_GRAPHS / 128), 256, 0, stream>>>(
        zpad, w1pad, b1, nullptr, z1h, z1l, N_GRAPHS, 2048, 80);
    // W2 (split-bf16 MFMA, K=2048) -> z2 hi/lo
    k_mfma_split<1><<<(1024 / 128) * (N_GRAPHS / 128), 256, 0, stream>>>(
        z1h, z1l, w2th, w2tl, b2, nullptr, z2h, z2l, 1024, 2048);
    // W3 (split-bf16 MFMA, K=1024) -> z3 fp32
    k_mfma_split<0><<<(128 / 128) * (N_GRAPHS / 128), 256, 0, stream>>>(
        z2h, z2l, w3th, w3tl, b3, z3, nullptr, nullptr, 128, 1024);

    // 5) heads (fp32, K=128)
    k_gemm<true, 0><<<dim3(256 / 128, N_GRAPHS / 128), 256, 0, stream>>>(
        z3, whcat, bh1p, ab, nullptr, nullptr, N_GRAPHS, 256, 128);
    k_heads_out<<<(N_GRAPHS * 6 + 255) / 256, 256, 0, stream>>>(ab, Wh2, bh2, out);
}

// Round 7
// 1223.577 us; speedup vs baseline: 1.3816x; 1.0227x over previous
//
#include <hip/hip_runtime.h>

#define N_NODES 500000
#define N_EDGES 2000000
#define N_GRAPHS 16384
#define STRIP 16
#define MPAD 500096          // 3907 * 128
#define KC1 192              // conv1 K padded 131 -> 192

#define SCAN_ELEMS 2048
#define SCAN_NBLK ((N_NODES + SCAN_ELEMS - 1) / SCAN_ELEMS)   // 245

typedef short bf16x8 __attribute__((ext_vector_type(8)));
typedef float f32x4 __attribute__((ext_vector_type(4)));
typedef unsigned short u16x8 __attribute__((ext_vector_type(8)));

__device__ __forceinline__ unsigned short f2bf_rne(float x) {
    unsigned int b = __float_as_uint(x);
    unsigned int r = (b + 0x7fffu + ((b >> 16) & 1u)) >> 16;
    return (unsigned short)r;
}
__device__ __forceinline__ float bf2f(unsigned short h) {
    return __uint_as_float(((unsigned int)h) << 16);
}
__device__ __forceinline__ void split_bf(float v, unsigned short& hi, unsigned short& lo) {
    hi = f2bf_rne(v);
    lo = f2bf_rne(v - bf2f(hi));
}

// ---------------- CSR build ----------------
__global__ __launch_bounds__(256) void k_zero_counts(int* counts) {
    int i = blockIdx.x * 256 + threadIdx.x;
    if (i < N_NODES) counts[i] = 0;
}
__global__ __launch_bounds__(256) void k_hist(const int* __restrict__ dst, int* __restrict__ counts) {
    int e = blockIdx.x * 256 + threadIdx.x;
    if (e < N_EDGES) atomicAdd(&counts[dst[e]], 1);
}
__global__ __launch_bounds__(256) void k_scan_reduce(const int* __restrict__ counts, int* __restrict__ bsum) {
    int b = blockIdx.x, t = threadIdx.x;
    int base_i = b * SCAN_ELEMS + t * 8;
    int s = 0;
    #pragma unroll
    for (int j = 0; j < 8; j++) { int i = base_i + j; if (i < N_NODES) s += counts[i]; }
    __shared__ int sh[256];
    sh[t] = s; __syncthreads();
    for (int off = 128; off > 0; off >>= 1) { if (t < off) sh[t] += sh[t + off]; __syncthreads(); }
    if (t == 0) bsum[b] = sh[0];
}
__global__ __launch_bounds__(256) void k_scan_bsum(const int* __restrict__ bsum, int* __restrict__ boff,
                                                   int* __restrict__ row_ptr) {
    __shared__ int sh[256];
    int t = threadIdx.x;
    int v = (t < SCAN_NBLK) ? bsum[t] : 0;
    sh[t] = v; __syncthreads();
    for (int off = 1; off < 256; off <<= 1) {
        int u = (t >= off) ? sh[t - off] : 0;
        __syncthreads();
        sh[t] += u; __syncthreads();
    }
    boff[t] = sh[t] - v;
    if (t == 255) row_ptr[N_NODES] = sh[255];
}
__global__ __launch_bounds__(256) void k_scan_final(const int* __restrict__ counts, const int* __restrict__ boff,
                                                    int* __restrict__ row_ptr, int* __restrict__ cursor,
                                                    float* __restrict__ dinv) {
    __shared__ int sh[256];
    int b = blockIdx.x, t = threadIdx.x;
    int base_i = b * SCAN_ELEMS + t * 8;
    int c[8]; int tsum = 0;
    #pragma unroll
    for (int j = 0; j < 8; j++) {
        int i = base_i + j;
        c[j] = (i < N_NODES) ? counts[i] : 0;
        tsum += c[j];
    }
    sh[t] = tsum; __syncthreads();
    for (int off = 1; off < 256; off <<= 1) {
        int u = (t >= off) ? sh[t - off] : 0;
        __syncthreads();
        sh[t] += u; __syncthreads();
    }
    int run = boff[b] + sh[t] - tsum;
    #pragma unroll
    for (int j = 0; j < 8; j++) {
        int i = base_i + j;
        if (i < N_NODES) {
            row_ptr[i] = run;
            cursor[i]  = run;
            dinv[i]    = rsqrtf((float)c[j] + 1.0f);
        }
        run += c[j];
    }
}
__global__ __launch_bounds__(256) void k_fill(const int* __restrict__ esrc, const int* __restrict__ edst,
                                              int* __restrict__ cursor, int* __restrict__ srcs) {
    int e = blockIdx.x * 256 + threadIdx.x;
    if (e >= N_EDGES) return;
    int d = edst[e];
    int pos = atomicAdd(&cursor[d], 1);
    srcs[pos] = esrc[e];
}
__global__ __launch_bounds__(256) void k_gstart(const int* __restrict__ batch, int* __restrict__ gstart) {
    int g = blockIdx.x * 256 + threadIdx.x;
    if (g > N_GRAPHS) return;
    if (g == N_GRAPHS) { gstart[g] = N_NODES; return; }
    int lo = 0, hi = N_NODES;
    while (lo < hi) { int mid = (lo + hi) >> 1; if (batch[mid] < g) lo = mid + 1; else hi = mid; }
    gstart[g] = lo;
}
__global__ __launch_bounds__(256) void k_zero_P(float* P) {
    int i = blockIdx.x * 256 + threadIdx.x;
    if (i < N_GRAPHS * 128) P[i] = 0.0f;
}

// ---------------- x -> padded bf16 [MPAD][192] ----------------
__global__ __launch_bounds__(256) void k_xsplit(const float* __restrict__ x, unsigned short* __restrict__ xb) {
    int idx = blockIdx.x * 256 + threadIdx.x;           // one per 8-col chunk
    if (idx >= MPAD * (KC1 / 8)) return;
    int n = idx / (KC1 / 8);
    int c8 = (idx % (KC1 / 8)) * 8;
    u16x8 o;
    #pragma unroll
    for (int j = 0; j < 8; j++) {
        int k = c8 + j;
        float v = (k < 131 && n < N_NODES) ? x[(size_t)n * 131 + k] : 0.0f;
        o[j] = f2bf_rne(v);
    }
    *(u16x8*)(xb + (size_t)n * KC1 + c8) = o;
}

// ---------------- Wc1 [131][128] -> transposed padded hi/lo [128][192] ----------------
__global__ __launch_bounds__(256) void k_wc1split(const float* __restrict__ W,
                                                  unsigned short* __restrict__ Th,
                                                  unsigned short* __restrict__ Tl) {
    int idx = blockIdx.x * 256 + threadIdx.x;
    if (idx >= 128 * KC1) return;
    int c = idx / KC1, k = idx % KC1;
    float v = (k < 131) ? W[(size_t)k * 128 + c] : 0.0f;
    unsigned short hi, lo; split_bf(v, hi, lo);
    Th[idx] = hi; Tl[idx] = lo;
}

// ---------------- conv1 MFMA GEMM: h_bf[M,128] = bf16( x_bf @ (Wh+Wl)^T ) ----------------
// A single bf16 [MPAD][192]; B hi/lo [128][192]. 128x128 tile, BK=64, 4 waves (2x2).
__global__ __launch_bounds__(256) void k_mfma_conv1(const unsigned short* __restrict__ Abf,
                                                    const unsigned short* __restrict__ Bh,
                                                    const unsigned short* __restrict__ Bl,
                                                    unsigned short* __restrict__ C) {
    __shared__ short lds[24576];   // A: 0..8191, Bh: 8192..16383, Bl: 16384..24575
    const int tid = threadIdx.x;
    const int w = tid >> 6, l = tid & 63;
    const int bm = blockIdx.x;
    const int wm = w >> 1, wn = w & 1;
    const int lane15 = l & 15, lg = l >> 4, l7 = l & 7;
    const int koffg = ((l & 7) ^ ((l >> 3) & 7)) * 8;   // pre-swizzled global col offset
    f32x4 acc[4][4] = {};
    for (int kt = 0; kt < 3; kt++) {
        const int k0 = kt * 64;
        __syncthreads();
        if (w < 2) {
            // waves 0,1: stage A rows [w*64, w*64+64)
            #pragma unroll
            for (int i = 0; i < 8; i++) {
                size_t row = (size_t)bm * 128 + w * 64 + i * 8 + (l >> 3);
                const unsigned short* src = Abf + row * KC1 + k0 + koffg;
                __builtin_amdgcn_global_load_lds(
                    (const __attribute__((address_space(1))) unsigned int*)src,
                    (__attribute__((address_space(3))) unsigned int*)&lds[w * 4096 + i * 512],
                    16, 0, 0);
            }
        } else {
            // wave 2: Bh, wave 3: Bl (128 rows)
            const unsigned short* gB = (w == 2) ? Bh : Bl;
            #pragma unroll
            for (int i = 0; i < 16; i++) {
                int row = i * 8 + (l >> 3);
                const unsigned short* src = gB + (size_t)row * KC1 + k0 + koffg;
                __builtin_amdgcn_global_load_lds(
                    (const __attribute__((address_space(1))) unsigned int*)src,
                    (__attribute__((address_space(3))) unsigned int*)&lds[(w - 1) * 8192 + i * 512],
                    16, 0, 0);
            }
        }
        __syncthreads();
        #pragma unroll
        for (int kh = 0; kh < 2; kh++) {
            const int slot = ((kh * 4 + lg) ^ l7) * 8;
            bf16x8 af[4], bhf[4], blf[4];
            #pragma unroll
            for (int m = 0; m < 4; m++)
                af[m] = *(const bf16x8*)&lds[(wm * 64 + m * 16 + lane15) * 64 + slot];
            #pragma unroll
            for (int n = 0; n < 4; n++) {
                int si = (wn * 64 + n * 16 + lane15) * 64 + slot;
                bhf[n] = *(const bf16x8*)&lds[8192 + si];
                blf[n] = *(const bf16x8*)&lds[16384 + si];
            }
            #pragma unroll
            for (int m = 0; m < 4; m++)
                #pragma unroll
                for (int n = 0; n < 4; n++) {
                    acc[m][n] = __builtin_amdgcn_mfma_f32_16x16x32_bf16(af[m], bhf[n], acc[m][n], 0, 0, 0);
                    acc[m][n] = __builtin_amdgcn_mfma_f32_16x16x32_bf16(af[m], blf[n], acc[m][n], 0, 0, 0);
                }
        }
    }
    const size_t row_b = (size_t)bm * 128 + wm * 64 + lg * 4;
    const int col_b = wn * 64 + lane15;
    #pragma unroll
    for (int m = 0; m < 4; m++)
        #pragma unroll
        for (int n = 0; n < 4; n++) {
            int col = col_b + n * 16;
            #pragma unroll
            for (int j = 0; j < 4; j++) {
                size_t row = row_b + m * 16 + j;
                if (row < N_NODES)
                    C[row * 128 + col] = f2bf_rne(acc[m][n][j]);
            }
        }
}

// ---------------- conv1 gather (bf16 in, fp32 accum, relu, bf16 out), edge loop x2 ----------------
__global__ __launch_bounds__(256) void k_gather1(const unsigned short* __restrict__ h,
                                                 const float* __restrict__ dinv,
                                                 const float* __restrict__ bias,
                                                 const int* __restrict__ row_ptr, const int* __restrict__ srcs,
                                                 unsigned short* __restrict__ r1) {
    int g = blockIdx.x * 256 + threadIdx.x;
    int n = g >> 6, lane = g & 63;
    if (n >= N_NODES) return;
    float dn = dinv[n];
    int c = lane * 2;
    unsigned int hv = *(const unsigned int*)(h + (size_t)n * 128 + c);
    float s2 = dn * dn;
    float a0 = fmaf(s2, bf2f((unsigned short)(hv & 0xffffu)), bias[c]);
    float a1 = fmaf(s2, bf2f((unsigned short)(hv >> 16)), bias[c + 1]);
    int e0 = row_ptr[n], e1 = row_ptr[n + 1];
    int e = e0;
    for (; e + 2 <= e1; e += 2) {
        int sA = srcs[e], sB = srcs[e + 1];
        float nA = dinv[sA] * dn, nB = dinv[sB] * dn;
        unsigned int hA = *(const unsigned int*)(h + (size_t)sA * 128 + c);
        unsigned int hB = *(const unsigned int*)(h + (size_t)sB * 128 + c);
        a0 = fmaf(nA, bf2f((unsigned short)(hA & 0xffffu)), a0);
        a1 = fmaf(nA, bf2f((unsigned short)(hA >> 16)), a1);
        a0 = fmaf(nB, bf2f((unsigned short)(hB & 0xffffu)), a0);
        a1 = fmaf(nB, bf2f((unsigned short)(hB >> 16)), a1);
    }
    if (e < e1) {
        int sA = srcs[e];
        float nA = dinv[sA] * dn;
        unsigned int hA = *(const unsigned int*)(h + (size_t)sA * 128 + c);
        a0 = fmaf(nA, bf2f((unsigned short)(hA & 0xffffu)), a0);
        a1 = fmaf(nA, bf2f((unsigned short)(hA >> 16)), a1);
    }
    a0 = fmaxf(a0, 0.0f);
    a1 = fmaxf(a1, 0.0f);
    unsigned int o = (unsigned int)f2bf_rne(a0) | ((unsigned int)f2bf_rne(a1) << 16);
    *(unsigned int*)(r1 + (size_t)n * 128 + c) = o;
}

// ---------------- fused conv2-agg + pool: wave-per-strip, register segment-sum, atomic flush ----------------
__global__ __launch_bounds__(256) void k_g2p(const unsigned short* __restrict__ r1,
                                             const float* __restrict__ dinv,
                                             const int* __restrict__ row_ptr, const int* __restrict__ srcs,
                                             const int* __restrict__ batch,
                                             float* __restrict__ P) {
    int gw = (blockIdx.x * 256 + threadIdx.x) >> 6;
    int lane = threadIdx.x & 63;
    if (gw >= N_NODES / STRIP) return;
    int n0 = gw * STRIP;
    int c = lane * 2;
    float a0 = 0.0f, a1 = 0.0f;
    int cur_g = batch[n0];
    for (int n = n0; n < n0 + STRIP; n++) {
        int bg = batch[n];
        if (bg != cur_g) {
            atomicAdd(&P[(size_t)cur_g * 128 + c], a0);
            atomicAdd(&P[(size_t)cur_g * 128 + c + 1], a1);
            a0 = a1 = 0.0f;
            cur_g = bg;
        }
        float dn = dinv[n];
        float s2 = dn * dn;
        unsigned int hv = *(const unsigned int*)(r1 + (size_t)n * 128 + c);
        a0 = fmaf(s2, bf2f((unsigned short)(hv & 0xffffu)), a0);
        a1 = fmaf(s2, bf2f((unsigned short)(hv >> 16)), a1);
        int e0 = row_ptr[n], e1 = row_ptr[n + 1];
        int e = e0;
        for (; e + 2 <= e1; e += 2) {
            int sA = srcs[e], sB = srcs[e + 1];
            float nA = dinv[sA] * dn, nB = dinv[sB] * dn;
            unsigned int hA = *(const unsigned int*)(r1 + (size_t)sA * 128 + c);
            unsigned int hB = *(const unsigned int*)(r1 + (size_t)sB * 128 + c);
            a0 = fmaf(nA, bf2f((unsigned short)(hA & 0xffffu)), a0);
            a1 = fmaf(nA, bf2f((unsigned short)(hA >> 16)), a1);
            a0 = fmaf(nB, bf2f((unsigned short)(hB & 0xffffu)), a0);
            a1 = fmaf(nB, bf2f((unsigned short)(hB >> 16)), a1);
        }
        if (e < e1) {
            int sA = srcs[e];
            float nA = dinv[sA] * dn;
            unsigned int hA = *(const unsigned int*)(r1 + (size_t)sA * 128 + c);
            a0 = fmaf(nA, bf2f((unsigned short)(hA & 0xffffu)), a0);
            a1 = fmaf(nA, bf2f((unsigned short)(hA >> 16)), a1);
        }
    }
    atomicAdd(&P[(size_t)cur_g * 128 + c], a0);
    atomicAdd(&P[(size_t)cur_g * 128 + c + 1], a1);
}

// ---------------- zpad build ----------------
__global__ __launch_bounds__(128) void k_zg(const float* __restrict__ P, const int* __restrict__ gstart,
                                            const float* __restrict__ Wc2, const float* __restrict__ bc2,
                                            const float* __restrict__ solv, float* __restrict__ zpad) {
    int g = blockIdx.x; int c = threadIdx.x;
    if (c >= 80) return;
    float v = 0.0f;
    if (c < 64) {
        const float* pr = P + (size_t)g * 128;
        float s = 0.0f;
        #pragma unroll 8
        for (int k = 0; k < 128; k++) s = fmaf(pr[k], Wc2[k * 64 + c], s);
        v = s + (float)(gstart[g + 1] - gstart[g]) * bc2[c];
    } else if (c < 75) {
        v = solv[g * 11 + (c - 64)];
    }
    zpad[(size_t)g * 80 + c] = v;
}

// ---------------- W1 pad 75->80 rows ----------------
__global__ __launch_bounds__(256) void k_w1pad(const float* __restrict__ W1, float* __restrict__ w1pad) {
    int i = blockIdx.x * 256 + threadIdx.x;
    if (i >= 80 * 2048) return;
    int r = i / 2048, c = i % 2048;
    w1pad[i] = (r < 75) ? W1[r * 2048 + c] : 0.0f;
}

// ---------------- heads weight concat ----------------
__global__ __launch_bounds__(256) void k_whcat(const float* __restrict__ Wh1, float* __restrict__ whcat) {
    int i = blockIdx.x * 256 + threadIdx.x;
    if (i >= 128 * 256) return;
    int f = i / 256, c = i % 256;
    float v = 0.0f;
    if (c < 192) {
        int h = c / 32, k = c & 31;
        v = Wh1[h * 128 * 32 + f * 32 + k];
    }
    whcat[i] = v;
}
__global__ __launch_bounds__(256) void k_bh1pad(const float* __restrict__ bh1, float* __restrict__ bh1pad) {
    int i = threadIdx.x;
    bh1pad[i] = (i < 192) ? bh1[i] : 0.0f;
}

// ---------------- transpose + hi/lo split ----------------
__global__ __launch_bounds__(256) void k_tsplit(const float* __restrict__ W, int R, int C,
                                                unsigned short* __restrict__ Th, unsigned short* __restrict__ Tl) {
    __shared__ float tile[64][65];
    int cb = blockIdx.x * 64, rb = blockIdx.y * 64;
    int tc = threadIdx.x & 63, tr4 = threadIdx.x >> 6;
    #pragma unroll 4
    for (int i = 0; i < 16; i++) {
        int r = tr4 + i * 4;
        tile[r][tc] = W[(size_t)(rb + r) * C + cb + tc];
    }
    __syncthreads();
    #pragma unroll 4
    for (int i = 0; i < 16; i++) {
        int r = tr4 + i * 4;
        float v = tile[tc][r];
        unsigned short hi, lo; split_bf(v, hi, lo);
        size_t o = (size_t)(cb + r) * R + rb + tc;
        Th[o] = hi; Tl[o] = lo;
    }
}

// ---------------- tiled fp32 GEMM: C = act(A @ B + bias); OMODE 0: fp32, 1: bf16 hi/lo ----------------
template<bool RELU, int OMODE>
__global__ __launch_bounds__(256) void k_gemm(const float* __restrict__ A,
                                              const float* __restrict__ B,
                                              const float* __restrict__ bias,
                                              float* __restrict__ C,
                                              unsigned short* __restrict__ Ch,
                                              unsigned short* __restrict__ Cl,
                                              int M, int N, int K) {
    __shared__ float As[8][132];
    __shared__ float Bs[8][132];
    const int tid = threadIdx.x;
    const int bm = blockIdx.y, bn = blockIdx.x;
    const int tr = (tid >> 4) << 3;
    const int tc = (tid & 15) << 3;
    float acc[8][8] = {};
    const float* Ab = A + (size_t)bm * 128 * K;
    const float* Bb = B + (size_t)bn * 128;
    const int la_r = tid >> 1, la_c = (tid & 1) << 2;
    const int lb_r = tid >> 5, lb_c = (tid & 31) << 2;
    for (int k0 = 0; k0 < K; k0 += 8) {
        float4 a4 = *(const float4*)(Ab + (size_t)la_r * K + k0 + la_c);
        float4 b4 = *(const float4*)(Bb + (size_t)(k0 + lb_r) * N + lb_c);
        __syncthreads();
        As[la_c + 0][la_r] = a4.x;
        As[la_c + 1][la_r] = a4.y;
        As[la_c + 2][la_r] = a4.z;
        As[la_c + 3][la_r] = a4.w;
        *(float4*)&Bs[lb_r][lb_c] = b4;
        __syncthreads();
        #pragma unroll
        for (int k = 0; k < 8; k++) {
            float a[8], b[8];
            *(float4*)&a[0] = *(const float4*)&As[k][tr];
            *(float4*)&a[4] = *(const float4*)&As[k][tr + 4];
            *(float4*)&b[0] = *(const float4*)&Bs[k][tc];
            *(float4*)&b[4] = *(const float4*)&Bs[k][tc + 4];
            #pragma unroll
            for (int i = 0; i < 8; i++)
                #pragma unroll
                for (int j = 0; j < 8; j++)
                    acc[i][j] = fmaf(a[i], b[j], acc[i][j]);
        }
    }
    const int row0 = bm * 128 + tr, col0 = bn * 128 + tc;
    #pragma unroll
    for (int i = 0; i < 8; i++) {
        if (OMODE == 0) {
            #pragma unroll
            for (int j = 0; j < 8; j++) {
                float v = acc[i][j] + bias[col0 + j];
                if (RELU) v = fmaxf(v, 0.0f);
                acc[i][j] = v;
            }
            *(float4*)(C + (size_t)(row0 + i) * N + col0)     = *(float4*)&acc[i][0];
            *(float4*)(C + (size_t)(row0 + i) * N + col0 + 4) = *(float4*)&acc[i][4];
        } else {
            u16x8 h8, l8;
            #pragma unroll
            for (int j = 0; j < 8; j++) {
                float v = acc[i][j] + bias[col0 + j];
                if (RELU) v = fmaxf(v, 0.0f);
                unsigned short hi, lo; split_bf(v, hi, lo);
                h8[j] = hi; l8[j] = lo;
            }
            *(u16x8*)(Ch + (size_t)(row0 + i) * N + col0) = h8;
            *(u16x8*)(Cl + (size_t)(row0 + i) * N + col0) = l8;
        }
    }
}

// ---------------- split-bf16 MFMA GEMM: C[M,N] = relu(A @ B^T + bias) ----------------
template<int OMODE>  // 0: fp32 out, 1: bf16 hi/lo out
__global__ __launch_bounds__(256) void k_mfma_split(
        const unsigned short* __restrict__ Ah, const unsigned short* __restrict__ Al,
        const unsigned short* __restrict__ Bh, const unsigned short* __restrict__ Bl,
        const float* __restrict__ bias,
        float* __restrict__ C, unsigned short* __restrict__ Ch, unsigned short* __restrict__ Cl,
        int N, int K) {
    __shared__ short lds[32768];   // 64 KB: 4 tiles [128 rows][64 bf16], swizzled
    const int tid = threadIdx.x;
    const int w = tid >> 6, l = tid & 63;
    const int id = blockIdx.x;
    const int bm = id & 127;
    const int bn = id >> 7;
    const unsigned short* gmat = (w == 0) ? Ah : (w == 1) ? Al : (w == 2) ? Bh : Bl;
    const size_t grow0 = (size_t)((w < 2) ? bm : bn) * 128 + (l >> 3);
    const int koffg = ((l & 7) ^ ((l >> 3) & 7)) * 8;
    const int ldsw = w * 8192;
    const int wm = w >> 1, wn = w & 1;
    const int lane15 = l & 15, lg = l >> 4, l7 = l & 7;
    f32x4 acc[4][4] = {};
    const int NK = K >> 6;
    for (int kt = 0; kt < NK; kt++) {
        const int k0 = kt << 6;
        __syncthreads();
        #pragma unroll
        for (int i = 0; i < 16; i++) {
            const unsigned short* src = gmat + (grow0 + (size_t)i * 8) * (size_t)K + k0 + koffg;
            __builtin_amdgcn_global_load_lds(
                (const __attribute__((address_space(1))) unsigned int*)src,
                (__attribute__((address_space(3))) unsigned int*)&lds[ldsw + i * 512],
                16, 0, 0);
        }
        __syncthreads();
        #pragma unroll
        for (int kh = 0; kh < 2; kh++) {
            const int slot = ((kh * 4 + lg) ^ l7) * 8;
            bf16x8 ahf[4], alf[4], bhf[4], blf[4];
            #pragma unroll
            for (int m = 0; m < 4; m++) {
                int si = (wm * 64 + m * 16 + lane15) * 64 + slot;
                ahf[m] = *(const bf16x8*)&lds[si];
                alf[m] = *(const bf16x8*)&lds[8192 + si];
            }
            #pragma unroll
            for (int n = 0; n < 4; n++) {
                int si = (wn * 64 + n * 16 + lane15) * 64 + slot;
                bhf[n] = *(const bf16x8*)&lds[16384 + si];
                blf[n] = *(const bf16x8*)&lds[24576 + si];
            }
            #pragma unroll
            for (int m = 0; m < 4; m++)
                #pragma unroll
                for (int n = 0; n < 4; n++) {
                    acc[m][n] = __builtin_amdgcn_mfma_f32_16x16x32_bf16(ahf[m], bhf[n], acc[m][n], 0, 0, 0);
                    acc[m][n] = __builtin_amdgcn_mfma_f32_16x16x32_bf16(ahf[m], blf[n], acc[m][n], 0, 0, 0);
                    acc[m][n] = __builtin_amdgcn_mfma_f32_16x16x32_bf16(alf[m], bhf[n], acc[m][n], 0, 0, 0);
                }
        }
    }
    const int row_b = bm * 128 + wm * 64 + lg * 4;
    const int col_b = bn * 128 + wn * 64 + lane15;
    #pragma unroll
    for (int m = 0; m < 4; m++)
        #pragma unroll
        for (int n = 0; n < 4; n++) {
            int col = col_b + n * 16;
            float bv = bias[col];
            #pragma unroll
            for (int j = 0; j < 4; j++) {
                int row = row_b + m * 16 + j;
                float v = fmaxf(acc[m][n][j] + bv, 0.0f);
                size_t o = (size_t)row * N + col;
                if (OMODE == 0) {
                    C[o] = v;
                } else {
                    unsigned short hi, lo; split_bf(v, hi, lo);
                    Ch[o] = hi; Cl[o] = lo;
                }
            }
        }
}

// ---------------- final heads reduce ----------------
__global__ __launch_bounds__(256) void k_heads_out(const float* __restrict__ a,
                                                   const float* __restrict__ Wh2,
                                                   const float* __restrict__ bh2,
                                                   float* __restrict__ out) {
    int i = blockIdx.x * 256 + threadIdx.x;
    if (i >= N_GRAPHS * 6) return;
    int g = i / 6, h = i % 6;
    const float* ap = a + (size_t)g * 256 + h * 32;
    const float* wp = Wh2 + h * 32;
    float s = 0.0f;
    #pragma unroll
    for (int k = 0; k < 32; k++) s = fmaf(ap[k], wp[k], s);
    out[i] = s + bh2[h];
}

extern "C" void kernel_launch(void* const* d_in, const int* in_sizes, int n_in,
                              void* d_out, int out_size, void* d_ws, size_t ws_size,
                              hipStream_t stream) {
    const float* x    = (const float*)d_in[0];
    const int*   esrc = (const int*)d_in[1];
    const int*   edst = (const int*)d_in[2];
    const int*   batch= (const int*)d_in[3];
    const float* solv = (const float*)d_in[4];
    const float* Wc1  = (const float*)d_in[5];
    const float* bc1  = (const float*)d_in[6];
    const float* Wc2  = (const float*)d_in[7];
    const float* bc2  = (const float*)d_in[8];
    const float* W1   = (const float*)d_in[9];
    const float* b1   = (const float*)d_in[10];
    const float* W2   = (const float*)d_in[11];
    const float* b2   = (const float*)d_in[12];
    const float* W3   = (const float*)d_in[13];
    const float* b3   = (const float*)d_in[14];
    const float* Wh1  = (const float*)d_in[15];
    const float* bh1  = (const float*)d_in[16];
    const float* Wh2  = (const float*)d_in[17];
    const float* bh2  = (const float*)d_in[18];
    float* out = (float*)d_out;

    // workspace layout (floats)
    float* ws    = (float*)d_ws;
    float* bufA  = ws;                             // 64,000,000 f
    float* bufB  = bufA + 64000000;                // 64,000,000 f
    float* dinv  = bufB + 64000000;                // 524,288 f
    float* zpad  = dinv + 524288;                  // 1,310,720 f
    float* w1pad = zpad + (size_t)N_GRAPHS * 80;   // 163,840 f
    float* whcat = w1pad + 80 * 2048;              // 32,768 f
    float* bh1p  = whcat + 128 * 256;              // 256 f
    int* counts  = (int*)(bh1p + 256);             // 500,000
    int* row_ptr = counts + N_NODES;               // 500,224
    int* cursor  = row_ptr + 500224;               // 500,000
    int* srcs    = cursor + N_NODES;               // 2,000,000
    int* bsum    = srcs + N_EDGES;                 // 256
    int* boff    = bsum + 256;                     // 256
    int* gstart  = boff + 256;                     // 16,640
    float* P     = bufB + 61902848;                // 2,097,152 f (tail of bufB)

    // conv activations / staging
    unsigned short* h_bf = (unsigned short*)bufA;  // [500k,128] u16 (bufA[0:32M f))
    unsigned short* x_bf = (unsigned short*)bufB;  // [MPAD,192] u16 = 48.01M f (dead after conv1)
    unsigned short* r1   = (unsigned short*)bufB;  // [500k,128] u16 (bufB[0:32M f)), after x_bf dead
    unsigned short* wc1h = (unsigned short*)(bufA + 60000000);  // 24,576 u16
    unsigned short* wc1l = wc1h + 128 * KC1;                    // 24,576 u16

    // hi/lo activations & weights (timeline-disjoint reuse)
    unsigned short* z1h = (unsigned short*)bufB;                // after r1 dead
    unsigned short* z1l = (unsigned short*)(bufB + 16800000);
    unsigned short* z2h = (unsigned short*)bufA;                // after h_bf dead
    unsigned short* z2l = (unsigned short*)(bufA + 8400000);
    float* z3 = bufB + 34000000;
    unsigned short* w2th = (unsigned short*)(bufA + 33000000);  // written after h_bf dead
    unsigned short* w2tl = (unsigned short*)(bufA + 34100000);
    unsigned short* w3th = (unsigned short*)(bufA + 35200000);
    unsigned short* w3tl = (unsigned short*)(bufA + 35300000);
    float* ab = bufA + 36000000;

    // 1) CSR build + dinv + graph segments + P zero
    k_zero_counts<<<(N_NODES + 255) / 256, 256, 0, stream>>>(counts);
    k_hist<<<(N_EDGES + 255) / 256, 256, 0, stream>>>(edst, counts);
    k_scan_reduce<<<SCAN_NBLK, 256, 0, stream>>>(counts, bsum);
    k_scan_bsum<<<1, 256, 0, stream>>>(bsum, boff, row_ptr);
    k_scan_final<<<SCAN_NBLK, 256, 0, stream>>>(counts, boff, row_ptr, cursor, dinv);
    k_fill<<<(N_EDGES + 255) / 256, 256, 0, stream>>>(esrc, edst, cursor, srcs);
    k_gstart<<<(N_GRAPHS + 256) / 256, 256, 0, stream>>>(batch, gstart);
    k_zero_P<<<(N_GRAPHS * 128) / 256, 256, 0, stream>>>(P);

    // 2) conv1 via MFMA: x -> x_bf (padded bf16) ; Wc1 -> hi/lo ; h_bf = bf16(x_bf @ Wc1)
    k_xsplit<<<(MPAD * (KC1 / 8) + 255) / 256, 256, 0, stream>>>(x, x_bf);
    k_wc1split<<<(128 * KC1 + 255) / 256, 256, 0, stream>>>(Wc1, wc1h, wc1l);
    k_mfma_conv1<<<MPAD / 128, 256, 0, stream>>>(x_bf, wc1h, wc1l, h_bf);

    // gather+relu -> r1 (bf16; overwrites x_bf region, which is dead now)
    k_gather1<<<(N_NODES * 64) / 256, 256, 0, stream>>>(h_bf, dinv, bc1, row_ptr, srcs, r1);

    // 3) fused conv2-agg + pool -> P (strip waves, register segment-sum, atomic flush)
    k_g2p<<<((N_NODES / STRIP) * 64 + 255) / 256, 256, 0, stream>>>(r1, dinv, row_ptr, srcs, batch, P);

    // weight transposes+splits
    k_tsplit<<<dim3(1024 / 64, 2048 / 64), 256, 0, stream>>>(W2, 2048, 1024, w2th, w2tl);
    k_tsplit<<<dim3(128 / 64, 1024 / 64), 256, 0, stream>>>(W3, 1024, 128, w3th, w3tl);

    k_zg<<<N_GRAPHS, 128, 0, stream>>>(P, gstart, Wc2, bc2, solv, zpad);

    // 4) MLP
    k_w1pad<<<(80 * 2048) / 256, 256, 0, stream>>>(W1, w1pad);
    k_whcat<<<(128 * 256) / 256, 256, 0, stream>>>(Wh1, whcat);
    k_bh1pad<<<1, 256, 0, stream>>>(bh1, bh1p);

    // W1 (fp32, K=80) -> z1 hi/lo
    k_gemm<true, 1><<<dim3(2048 / 128, N_GRAPHS / 128), 256, 0, stream>>>(
        zpad, w1pad, b1, nullptr, z1h, z1l, N_GRAPHS, 2048, 80);
    // W2 (split-bf16 MFMA, K=2048) -> z2 hi/lo
    k_mfma_split<1><<<(1024 / 128) * (N_GRAPHS / 128), 256, 0, stream>>>(
        z1h, z1l, w2th, w2tl, b2, nullptr, z2h, z2l, 1024, 2048);
    // W3 (split-bf16 MFMA, K=1024) -> z3 fp32
    k_mfma_split<0><<<(128 / 128) * (N_GRAPHS / 128), 256, 0, stream>>>(
        z2h, z2l, w3th, w3tl, b3, z3, nullptr, nullptr, 128, 1024);

    // 5) heads (fp32, K=128)
    k_gemm<true, 0><<<dim3(256 / 128, N_GRAPHS / 128), 256, 0, stream>>>(
        z3, whcat, bh1p, ab, nullptr, nullptr, N_GRAPHS, 256, 128);
    k_heads_out<<<(N_GRAPHS * 6 + 255) / 256, 256, 0, stream>>>(ab, Wh2, bh2, out);
}

// Round 8
// 1123.046 us; speedup vs baseline: 1.5053x; 1.0895x over previous
//
#include <hip/hip_runtime.h>

#define N_NODES 500000
#define N_EDGES 2000000
#define N_GRAPHS 16384
#define STRIP 16
#define KC1 192              // conv1 K padded 131 -> 192

#define SCAN_ELEMS 2048
#define SCAN_NBLK ((N_NODES + SCAN_ELEMS - 1) / SCAN_ELEMS)   // 245

typedef short bf16x8 __attribute__((ext_vector_type(8)));
typedef float f32x4 __attribute__((ext_vector_type(4)));
typedef unsigned short u16x8 __attribute__((ext_vector_type(8)));

__device__ __forceinline__ unsigned short f2bf_rne(float x) {
    unsigned int b = __float_as_uint(x);
    unsigned int r = (b + 0x7fffu + ((b >> 16) & 1u)) >> 16;
    return (unsigned short)r;
}
__device__ __forceinline__ float bf2f(unsigned short h) {
    return __uint_as_float(((unsigned int)h) << 16);
}
__device__ __forceinline__ void split_bf(float v, unsigned short& hi, unsigned short& lo) {
    hi = f2bf_rne(v);
    lo = f2bf_rne(v - bf2f(hi));
}

// ---------------- CSR build ----------------
__global__ __launch_bounds__(256) void k_zero_counts(int* counts) {
    int i = blockIdx.x * 256 + threadIdx.x;
    if (i < N_NODES) counts[i] = 0;
}
__global__ __launch_bounds__(256) void k_hist(const int* __restrict__ dst, int* __restrict__ counts) {
    int e = blockIdx.x * 256 + threadIdx.x;
    if (e < N_EDGES) atomicAdd(&counts[dst[e]], 1);
}
__global__ __launch_bounds__(256) void k_scan_reduce(const int* __restrict__ counts, int* __restrict__ bsum) {
    int b = blockIdx.x, t = threadIdx.x;
    int base_i = b * SCAN_ELEMS + t * 8;
    int s = 0;
    #pragma unroll
    for (int j = 0; j < 8; j++) { int i = base_i + j; if (i < N_NODES) s += counts[i]; }
    __shared__ int sh[256];
    sh[t] = s; __syncthreads();
    for (int off = 128; off > 0; off >>= 1) { if (t < off) sh[t] += sh[t + off]; __syncthreads(); }
    if (t == 0) bsum[b] = sh[0];
}
__global__ __launch_bounds__(256) void k_scan_bsum(const int* __restrict__ bsum, int* __restrict__ boff,
                                                   int* __restrict__ row_ptr) {
    __shared__ int sh[256];
    int t = threadIdx.x;
    int v = (t < SCAN_NBLK) ? bsum[t] : 0;
    sh[t] = v; __syncthreads();
    for (int off = 1; off < 256; off <<= 1) {
        int u = (t >= off) ? sh[t - off] : 0;
        __syncthreads();
        sh[t] += u; __syncthreads();
    }
    boff[t] = sh[t] - v;
    if (t == 255) row_ptr[N_NODES] = sh[255];
}
__global__ __launch_bounds__(256) void k_scan_final(const int* __restrict__ counts, const int* __restrict__ boff,
                                                    int* __restrict__ row_ptr, int* __restrict__ cursor,
                                                    float* __restrict__ dinv) {
    __shared__ int sh[256];
    int b = blockIdx.x, t = threadIdx.x;
    int base_i = b * SCAN_ELEMS + t * 8;
    int c[8]; int tsum = 0;
    #pragma unroll
    for (int j = 0; j < 8; j++) {
        int i = base_i + j;
        c[j] = (i < N_NODES) ? counts[i] : 0;
        tsum += c[j];
    }
    sh[t] = tsum; __syncthreads();
    for (int off = 1; off < 256; off <<= 1) {
        int u = (t >= off) ? sh[t - off] : 0;
        __syncthreads();
        sh[t] += u; __syncthreads();
    }
    int run = boff[b] + sh[t] - tsum;
    #pragma unroll
    for (int j = 0; j < 8; j++) {
        int i = base_i + j;
        if (i < N_NODES) {
            row_ptr[i] = run;
            cursor[i]  = run;
            dinv[i]    = rsqrtf((float)c[j] + 1.0f);
        }
        run += c[j];
    }
}
__global__ __launch_bounds__(256) void k_fill(const int* __restrict__ esrc, const int* __restrict__ edst,
                                              int* __restrict__ cursor, int* __restrict__ srcs) {
    int e = blockIdx.x * 256 + threadIdx.x;
    if (e >= N_EDGES) return;
    int d = edst[e];
    int pos = atomicAdd(&cursor[d], 1);
    srcs[pos] = esrc[e];
}
__global__ __launch_bounds__(256) void k_gstart(const int* __restrict__ batch, int* __restrict__ gstart) {
    int g = blockIdx.x * 256 + threadIdx.x;
    if (g > N_GRAPHS) return;
    if (g == N_GRAPHS) { gstart[g] = N_NODES; return; }
    int lo = 0, hi = N_NODES;
    while (lo < hi) { int mid = (lo + hi) >> 1; if (batch[mid] < g) lo = mid + 1; else hi = mid; }
    gstart[g] = lo;
}
__global__ __launch_bounds__(256) void k_zero_P(float* P) {
    int i = blockIdx.x * 256 + threadIdx.x;
    if (i < N_GRAPHS * 128) P[i] = 0.0f;
}

// ---------------- Wc1 [131][128] -> transposed padded hi/lo [128][192] ----------------
__global__ __launch_bounds__(256) void k_wc1split(const float* __restrict__ W,
                                                  unsigned short* __restrict__ Th,
                                                  unsigned short* __restrict__ Tl) {
    int idx = blockIdx.x * 256 + threadIdx.x;
    if (idx >= 128 * KC1) return;
    int c = idx / KC1, k = idx % KC1;
    float v = (k < 131) ? W[(size_t)k * 128 + c] : 0.0f;
    unsigned short hi, lo; split_bf(v, hi, lo);
    Th[idx] = hi; Tl[idx] = lo;
}

// ---------------- conv1 MFMA GEMM, fused x->bf16 staging ----------------
// h_bf[M,128] = bf16( bf16(x)[M,131] @ (Wh+Wl)^T ). A reg-staged from fp32 x; B hi/lo [128][192].
__global__ __launch_bounds__(256) void k_mfma_conv1(const float* __restrict__ X,
                                                    const unsigned short* __restrict__ Bh,
                                                    const unsigned short* __restrict__ Bl,
                                                    unsigned short* __restrict__ C) {
    __shared__ short lds[24576];   // A: 0..8191, Bh: 8192..16383, Bl: 16384..24575
    const int tid = threadIdx.x;
    const int w = tid >> 6, l = tid & 63;
    const int bm = blockIdx.x;
    const int wm = w >> 1, wn = w & 1;
    const int lane15 = l & 15, lg = l >> 4, l7 = l & 7;
    const int koffg = ((l & 7) ^ ((l >> 3) & 7)) * 8;   // pre-swizzled col offset within 64-chunk
    f32x4 acc[4][4] = {};
    for (int kt = 0; kt < 3; kt++) {
        const int k0 = kt * 64;
        u16x8 a_st[8];
        if (w < 2) {
            // reg-load fp32 x, convert to bf16 (no LDS touch yet)
            #pragma unroll
            for (int i = 0; i < 8; i++) {
                int row = bm * 128 + w * 64 + i * 8 + (l >> 3);
                if (row >= N_NODES) row = N_NODES - 1;
                const float* src = X + (size_t)row * 131 + k0 + koffg;
                if (kt < 2) {
                    #pragma unroll
                    for (int j = 0; j < 8; j++) a_st[i][j] = f2bf_rne(src[j]);
                } else {
                    #pragma unroll
                    for (int j = 0; j < 8; j++) {
                        int k = k0 + koffg + j;
                        a_st[i][j] = (k < 131) ? f2bf_rne(src[j]) : (unsigned short)0;
                    }
                }
            }
        }
        __syncthreads();   // previous compute done; LDS safe to overwrite
        if (w < 2) {
            #pragma unroll
            for (int i = 0; i < 8; i++)
                *(u16x8*)&lds[w * 4096 + i * 512 + l * 8] = a_st[i];
        } else {
            const unsigned short* gB = (w == 2) ? Bh : Bl;
            #pragma unroll
            for (int i = 0; i < 16; i++) {
                int row = i * 8 + (l >> 3);
                const unsigned short* src = gB + (size_t)row * KC1 + k0 + koffg;
                __builtin_amdgcn_global_load_lds(
                    (const __attribute__((address_space(1))) unsigned int*)src,
                    (__attribute__((address_space(3))) unsigned int*)&lds[(w - 1) * 8192 + i * 512],
                    16, 0, 0);
            }
        }
        __syncthreads();   // staging visible
        #pragma unroll
        for (int kh = 0; kh < 2; kh++) {
            const int slot = ((kh * 4 + lg) ^ l7) * 8;
            bf16x8 af[4], bhf[4], blf[4];
            #pragma unroll
            for (int m = 0; m < 4; m++)
                af[m] = *(const bf16x8*)&lds[(wm * 64 + m * 16 + lane15) * 64 + slot];
            #pragma unroll
            for (int n = 0; n < 4; n++) {
                int si = (wn * 64 + n * 16 + lane15) * 64 + slot;
                bhf[n] = *(const bf16x8*)&lds[8192 + si];
                blf[n] = *(const bf16x8*)&lds[16384 + si];
            }
            #pragma unroll
            for (int m = 0; m < 4; m++)
                #pragma unroll
                for (int n = 0; n < 4; n++) {
                    acc[m][n] = __builtin_amdgcn_mfma_f32_16x16x32_bf16(af[m], bhf[n], acc[m][n], 0, 0, 0);
                    acc[m][n] = __builtin_amdgcn_mfma_f32_16x16x32_bf16(af[m], blf[n], acc[m][n], 0, 0, 0);
                }
        }
    }
    const size_t row_b = (size_t)bm * 128 + wm * 64 + lg * 4;
    const int col_b = wn * 64 + lane15;
    #pragma unroll
    for (int m = 0; m < 4; m++)
        #pragma unroll
        for (int n = 0; n < 4; n++) {
            int col = col_b + n * 16;
            #pragma unroll
            for (int j = 0; j < 4; j++) {
                size_t row = row_b + m * 16 + j;
                if (row < N_NODES)
                    C[row * 128 + col] = f2bf_rne(acc[m][n][j]);
            }
        }
}

// ---------------- conv1 gather (bf16 in, fp32 accum, relu, bf16 nt-out), edge loop x4 ----------------
__global__ __launch_bounds__(256) void k_gather1(const unsigned short* __restrict__ h,
                                                 const float* __restrict__ dinv,
                                                 const float* __restrict__ bias,
                                                 const int* __restrict__ row_ptr, const int* __restrict__ srcs,
                                                 unsigned short* __restrict__ r1) {
    int g = blockIdx.x * 256 + threadIdx.x;
    int n = g >> 6, lane = g & 63;
    if (n >= N_NODES) return;
    float dn = dinv[n];
    int c = lane * 2;
    unsigned int hv = *(const unsigned int*)(h + (size_t)n * 128 + c);
    float s2 = dn * dn;
    float a0 = fmaf(s2, bf2f((unsigned short)(hv & 0xffffu)), bias[c]);
    float a1 = fmaf(s2, bf2f((unsigned short)(hv >> 16)), bias[c + 1]);
    int e0 = row_ptr[n], e1 = row_ptr[n + 1];
    int e = e0;
    for (; e + 4 <= e1; e += 4) {
        int sA = srcs[e], sB = srcs[e + 1], sC = srcs[e + 2], sD = srcs[e + 3];
        float nA = dinv[sA] * dn, nB = dinv[sB] * dn, nC = dinv[sC] * dn, nD = dinv[sD] * dn;
        unsigned int hA = *(const unsigned int*)(h + (size_t)sA * 128 + c);
        unsigned int hB = *(const unsigned int*)(h + (size_t)sB * 128 + c);
        unsigned int hC = *(const unsigned int*)(h + (size_t)sC * 128 + c);
        unsigned int hD = *(const unsigned int*)(h + (size_t)sD * 128 + c);
        a0 = fmaf(nA, bf2f((unsigned short)(hA & 0xffffu)), a0);
        a1 = fmaf(nA, bf2f((unsigned short)(hA >> 16)), a1);
        a0 = fmaf(nB, bf2f((unsigned short)(hB & 0xffffu)), a0);
        a1 = fmaf(nB, bf2f((unsigned short)(hB >> 16)), a1);
        a0 = fmaf(nC, bf2f((unsigned short)(hC & 0xffffu)), a0);
        a1 = fmaf(nC, bf2f((unsigned short)(hC >> 16)), a1);
        a0 = fmaf(nD, bf2f((unsigned short)(hD & 0xffffu)), a0);
        a1 = fmaf(nD, bf2f((unsigned short)(hD >> 16)), a1);
    }
    for (; e < e1; e++) {
        int sA = srcs[e];
        float nA = dinv[sA] * dn;
        unsigned int hA = *(const unsigned int*)(h + (size_t)sA * 128 + c);
        a0 = fmaf(nA, bf2f((unsigned short)(hA & 0xffffu)), a0);
        a1 = fmaf(nA, bf2f((unsigned short)(hA >> 16)), a1);
    }
    a0 = fmaxf(a0, 0.0f);
    a1 = fmaxf(a1, 0.0f);
    unsigned int o = (unsigned int)f2bf_rne(a0) | ((unsigned int)f2bf_rne(a1) << 16);
    __builtin_nontemporal_store(o, (unsigned int*)(r1 + (size_t)n * 128 + c));
}

// ---------------- fused conv2-agg + pool: wave-per-strip, register segment-sum, atomic flush ----------------
__global__ __launch_bounds__(256) void k_g2p(const unsigned short* __restrict__ r1,
                                             const float* __restrict__ dinv,
                                             const int* __restrict__ row_ptr, const int* __restrict__ srcs,
                                             const int* __restrict__ batch,
                                             float* __restrict__ P) {
    int gw = (blockIdx.x * 256 + threadIdx.x) >> 6;
    int lane = threadIdx.x & 63;
    if (gw >= N_NODES / STRIP) return;
    int n0 = gw * STRIP;
    int c = lane * 2;
    float a0 = 0.0f, a1 = 0.0f;
    int cur_g = batch[n0];
    for (int n = n0; n < n0 + STRIP; n++) {
        int bg = batch[n];
        if (bg != cur_g) {
            atomicAdd(&P[(size_t)cur_g * 128 + c], a0);
            atomicAdd(&P[(size_t)cur_g * 128 + c + 1], a1);
            a0 = a1 = 0.0f;
            cur_g = bg;
        }
        float dn = dinv[n];
        float s2 = dn * dn;
        unsigned int hv = *(const unsigned int*)(r1 + (size_t)n * 128 + c);
        a0 = fmaf(s2, bf2f((unsigned short)(hv & 0xffffu)), a0);
        a1 = fmaf(s2, bf2f((unsigned short)(hv >> 16)), a1);
        int e0 = row_ptr[n], e1 = row_ptr[n + 1];
        int e = e0;
        for (; e + 4 <= e1; e += 4) {
            int sA = srcs[e], sB = srcs[e + 1], sC = srcs[e + 2], sD = srcs[e + 3];
            float nA = dinv[sA] * dn, nB = dinv[sB] * dn, nC = dinv[sC] * dn, nD = dinv[sD] * dn;
            unsigned int hA = *(const unsigned int*)(r1 + (size_t)sA * 128 + c);
            unsigned int hB = *(const unsigned int*)(r1 + (size_t)sB * 128 + c);
            unsigned int hC = *(const unsigned int*)(r1 + (size_t)sC * 128 + c);
            unsigned int hD = *(const unsigned int*)(r1 + (size_t)sD * 128 + c);
            a0 = fmaf(nA, bf2f((unsigned short)(hA & 0xffffu)), a0);
            a1 = fmaf(nA, bf2f((unsigned short)(hA >> 16)), a1);
            a0 = fmaf(nB, bf2f((unsigned short)(hB & 0xffffu)), a0);
            a1 = fmaf(nB, bf2f((unsigned short)(hB >> 16)), a1);
            a0 = fmaf(nC, bf2f((unsigned short)(hC & 0xffffu)), a0);
            a1 = fmaf(nC, bf2f((unsigned short)(hC >> 16)), a1);
            a0 = fmaf(nD, bf2f((unsigned short)(hD & 0xffffu)), a0);
            a1 = fmaf(nD, bf2f((unsigned short)(hD >> 16)), a1);
        }
        for (; e < e1; e++) {
            int sA = srcs[e];
            float nA = dinv[sA] * dn;
            unsigned int hA = *(const unsigned int*)(r1 + (size_t)sA * 128 + c);
            a0 = fmaf(nA, bf2f((unsigned short)(hA & 0xffffu)), a0);
            a1 = fmaf(nA, bf2f((unsigned short)(hA >> 16)), a1);
        }
    }
    atomicAdd(&P[(size_t)cur_g * 128 + c], a0);
    atomicAdd(&P[(size_t)cur_g * 128 + c + 1], a1);
}

// ---------------- zpad build ----------------
__global__ __launch_bounds__(128) void k_zg(const float* __restrict__ P, const int* __restrict__ gstart,
                                            const float* __restrict__ Wc2, const float* __restrict__ bc2,
                                            const float* __restrict__ solv, float* __restrict__ zpad) {
    int g = blockIdx.x; int c = threadIdx.x;
    if (c >= 80) return;
    float v = 0.0f;
    if (c < 64) {
        const float* pr = P + (size_t)g * 128;
        float s = 0.0f;
        #pragma unroll 8
        for (int k = 0; k < 128; k++) s = fmaf(pr[k], Wc2[k * 64 + c], s);
        v = s + (float)(gstart[g + 1] - gstart[g]) * bc2[c];
    } else if (c < 75) {
        v = solv[g * 11 + (c - 64)];
    }
    zpad[(size_t)g * 80 + c] = v;
}

// ---------------- W1 pad 75->80 rows ----------------
__global__ __launch_bounds__(256) void k_w1pad(const float* __restrict__ W1, float* __restrict__ w1pad) {
    int i = blockIdx.x * 256 + threadIdx.x;
    if (i >= 80 * 2048) return;
    int r = i / 2048, c = i % 2048;
    w1pad[i] = (r < 75) ? W1[r * 2048 + c] : 0.0f;
}

// ---------------- heads weight concat ----------------
__global__ __launch_bounds__(256) void k_whcat(const float* __restrict__ Wh1, float* __restrict__ whcat) {
    int i = blockIdx.x * 256 + threadIdx.x;
    if (i >= 128 * 256) return;
    int f = i / 256, c = i % 256;
    float v = 0.0f;
    if (c < 192) {
        int h = c / 32, k = c & 31;
        v = Wh1[h * 128 * 32 + f * 32 + k];
    }
    whcat[i] = v;
}
__global__ __launch_bounds__(256) void k_bh1pad(const float* __restrict__ bh1, float* __restrict__ bh1pad) {
    int i = threadIdx.x;
    bh1pad[i] = (i < 192) ? bh1[i] : 0.0f;
}

// ---------------- transpose + hi/lo split ----------------
__global__ __launch_bounds__(256) void k_tsplit(const float* __restrict__ W, int R, int C,
                                                unsigned short* __restrict__ Th, unsigned short* __restrict__ Tl) {
    __shared__ float tile[64][65];
    int cb = blockIdx.x * 64, rb = blockIdx.y * 64;
    int tc = threadIdx.x & 63, tr4 = threadIdx.x >> 6;
    #pragma unroll 4
    for (int i = 0; i < 16; i++) {
        int r = tr4 + i * 4;
        tile[r][tc] = W[(size_t)(rb + r) * C + cb + tc];
    }
    __syncthreads();
    #pragma unroll 4
    for (int i = 0; i < 16; i++) {
        int r = tr4 + i * 4;
        float v = tile[tc][r];
        unsigned short hi, lo; split_bf(v, hi, lo);
        size_t o = (size_t)(cb + r) * R + rb + tc;
        Th[o] = hi; Tl[o] = lo;
    }
}

// ---------------- tiled fp32 GEMM: C = act(A @ B + bias); OMODE 0: fp32, 1: bf16 hi/lo ----------------
template<bool RELU, int OMODE>
__global__ __launch_bounds__(256) void k_gemm(const float* __restrict__ A,
                                              const float* __restrict__ B,
                                              const float* __restrict__ bias,
                                              float* __restrict__ C,
                                              unsigned short* __restrict__ Ch,
                                              unsigned short* __restrict__ Cl,
                                              int M, int N, int K) {
    __shared__ float As[8][132];
    __shared__ float Bs[8][132];
    const int tid = threadIdx.x;
    const int bm = blockIdx.y, bn = blockIdx.x;
    const int tr = (tid >> 4) << 3;
    const int tc = (tid & 15) << 3;
    float acc[8][8] = {};
    const float* Ab = A + (size_t)bm * 128 * K;
    const float* Bb = B + (size_t)bn * 128;
    const int la_r = tid >> 1, la_c = (tid & 1) << 2;
    const int lb_r = tid >> 5, lb_c = (tid & 31) << 2;
    for (int k0 = 0; k0 < K; k0 += 8) {
        float4 a4 = *(const float4*)(Ab + (size_t)la_r * K + k0 + la_c);
        float4 b4 = *(const float4*)(Bb + (size_t)(k0 + lb_r) * N + lb_c);
        __syncthreads();
        As[la_c + 0][la_r] = a4.x;
        As[la_c + 1][la_r] = a4.y;
        As[la_c + 2][la_r] = a4.z;
        As[la_c + 3][la_r] = a4.w;
        *(float4*)&Bs[lb_r][lb_c] = b4;
        __syncthreads();
        #pragma unroll
        for (int k = 0; k < 8; k++) {
            float a[8], b[8];
            *(float4*)&a[0] = *(const float4*)&As[k][tr];
            *(float4*)&a[4] = *(const float4*)&As[k][tr + 4];
            *(float4*)&b[0] = *(const float4*)&Bs[k][tc];
            *(float4*)&b[4] = *(const float4*)&Bs[k][tc + 4];
            #pragma unroll
            for (int i = 0; i < 8; i++)
                #pragma unroll
                for (int j = 0; j < 8; j++)
                    acc[i][j] = fmaf(a[i], b[j], acc[i][j]);
        }
    }
    const int row0 = bm * 128 + tr, col0 = bn * 128 + tc;
    #pragma unroll
    for (int i = 0; i < 8; i++) {
        if (OMODE == 0) {
            #pragma unroll
            for (int j = 0; j < 8; j++) {
                float v = acc[i][j] + bias[col0 + j];
                if (RELU) v = fmaxf(v, 0.0f);
                acc[i][j] = v;
            }
            *(float4*)(C + (size_t)(row0 + i) * N + col0)     = *(float4*)&acc[i][0];
            *(float4*)(C + (size_t)(row0 + i) * N + col0 + 4) = *(float4*)&acc[i][4];
        } else {
            u16x8 h8, l8;
            #pragma unroll
            for (int j = 0; j < 8; j++) {
                float v = acc[i][j] + bias[col0 + j];
                if (RELU) v = fmaxf(v, 0.0f);
                unsigned short hi, lo; split_bf(v, hi, lo);
                h8[j] = hi; l8[j] = lo;
            }
            *(u16x8*)(Ch + (size_t)(row0 + i) * N + col0) = h8;
            *(u16x8*)(Cl + (size_t)(row0 + i) * N + col0) = l8;
        }
    }
}

// ---------------- split-bf16 MFMA GEMM: C[M,N] = relu(A @ B^T + bias) ----------------
template<int OMODE>  // 0: fp32 out, 1: bf16 hi/lo out
__global__ __launch_bounds__(256) void k_mfma_split(
        const unsigned short* __restrict__ Ah, const unsigned short* __restrict__ Al,
        const unsigned short* __restrict__ Bh, const unsigned short* __restrict__ Bl,
        const float* __restrict__ bias,
        float* __restrict__ C, unsigned short* __restrict__ Ch, unsigned short* __restrict__ Cl,
        int N, int K) {
    __shared__ short lds[32768];   // 64 KB: 4 tiles [128 rows][64 bf16], swizzled
    const int tid = threadIdx.x;
    const int w = tid >> 6, l = tid & 63;
    const int id = blockIdx.x;
    const int bm = id & 127;
    const int bn = id >> 7;
    const unsigned short* gmat = (w == 0) ? Ah : (w == 1) ? Al : (w == 2) ? Bh : Bl;
    const size_t grow0 = (size_t)((w < 2) ? bm : bn) * 128 + (l >> 3);
    const int koffg = ((l & 7) ^ ((l >> 3) & 7)) * 8;
    const int ldsw = w * 8192;
    const int wm = w >> 1, wn = w & 1;
    const int lane15 = l & 15, lg = l >> 4, l7 = l & 7;
    f32x4 acc[4][4] = {};
    const int NK = K >> 6;
    for (int kt = 0; kt < NK; kt++) {
        const int k0 = kt << 6;
        __syncthreads();
        #pragma unroll
        for (int i = 0; i < 16; i++) {
            const unsigned short* src = gmat + (grow0 + (size_t)i * 8) * (size_t)K + k0 + koffg;
            __builtin_amdgcn_global_load_lds(
                (const __attribute__((address_space(1))) unsigned int*)src,
                (__attribute__((address_space(3))) unsigned int*)&lds[ldsw + i * 512],
                16, 0, 0);
        }
        __syncthreads();
        #pragma unroll
        for (int kh = 0; kh < 2; kh++) {
            const int slot = ((kh * 4 + lg) ^ l7) * 8;
            bf16x8 ahf[4], alf[4], bhf[4], blf[4];
            #pragma unroll
            for (int m = 0; m < 4; m++) {
                int si = (wm * 64 + m * 16 + lane15) * 64 + slot;
                ahf[m] = *(const bf16x8*)&lds[si];
                alf[m] = *(const bf16x8*)&lds[8192 + si];
            }
            #pragma unroll
            for (int n = 0; n < 4; n++) {
                int si = (wn * 64 + n * 16 + lane15) * 64 + slot;
                bhf[n] = *(const bf16x8*)&lds[16384 + si];
                blf[n] = *(const bf16x8*)&lds[24576 + si];
            }
            #pragma unroll
            for (int m = 0; m < 4; m++)
                #pragma unroll
                for (int n = 0; n < 4; n++) {
                    acc[m][n] = __builtin_amdgcn_mfma_f32_16x16x32_bf16(ahf[m], bhf[n], acc[m][n], 0, 0, 0);
                    acc[m][n] = __builtin_amdgcn_mfma_f32_16x16x32_bf16(ahf[m], blf[n], acc[m][n], 0, 0, 0);
                    acc[m][n] = __builtin_amdgcn_mfma_f32_16x16x32_bf16(alf[m], bhf[n], acc[m][n], 0, 0, 0);
                }
        }
    }
    const int row_b = bm * 128 + wm * 64 + lg * 4;
    const int col_b = bn * 128 + wn * 64 + lane15;
    #pragma unroll
    for (int m = 0; m < 4; m++)
        #pragma unroll
        for (int n = 0; n < 4; n++) {
            int col = col_b + n * 16;
            float bv = bias[col];
            #pragma unroll
            for (int j = 0; j < 4; j++) {
                int row = row_b + m * 16 + j;
                float v = fmaxf(acc[m][n][j] + bv, 0.0f);
                size_t o = (size_t)row * N + col;
                if (OMODE == 0) {
                    C[o] = v;
                } else {
                    unsigned short hi, lo; split_bf(v, hi, lo);
                    Ch[o] = hi; Cl[o] = lo;
                }
            }
        }
}

// ---------------- final heads reduce ----------------
__global__ __launch_bounds__(256) void k_heads_out(const float* __restrict__ a,
                                                   const float* __restrict__ Wh2,
                                                   const float* __restrict__ bh2,
                                                   float* __restrict__ out) {
    int i = blockIdx.x * 256 + threadIdx.x;
    if (i >= N_GRAPHS * 6) return;
    int g = i / 6, h = i % 6;
    const float* ap = a + (size_t)g * 256 + h * 32;
    const float* wp = Wh2 + h * 32;
    float s = 0.0f;
    #pragma unroll
    for (int k = 0; k < 32; k++) s = fmaf(ap[k], wp[k], s);
    out[i] = s + bh2[h];
}

extern "C" void kernel_launch(void* const* d_in, const int* in_sizes, int n_in,
                              void* d_out, int out_size, void* d_ws, size_t ws_size,
                              hipStream_t stream) {
    const float* x    = (const float*)d_in[0];
    const int*   esrc = (const int*)d_in[1];
    const int*   edst = (const int*)d_in[2];
    const int*   batch= (const int*)d_in[3];
    const float* solv = (const float*)d_in[4];
    const float* Wc1  = (const float*)d_in[5];
    const float* bc1  = (const float*)d_in[6];
    const float* Wc2  = (const float*)d_in[7];
    const float* bc2  = (const float*)d_in[8];
    const float* W1   = (const float*)d_in[9];
    const float* b1   = (const float*)d_in[10];
    const float* W2   = (const float*)d_in[11];
    const float* b2   = (const float*)d_in[12];
    const float* W3   = (const float*)d_in[13];
    const float* b3   = (const float*)d_in[14];
    const float* Wh1  = (const float*)d_in[15];
    const float* bh1  = (const float*)d_in[16];
    const float* Wh2  = (const float*)d_in[17];
    const float* bh2  = (const float*)d_in[18];
    float* out = (float*)d_out;

    // workspace layout (floats)
    float* ws    = (float*)d_ws;
    float* bufA  = ws;                             // 64,000,000 f
    float* bufB  = bufA + 64000000;                // 64,000,000 f
    float* dinv  = bufB + 64000000;                // 524,288 f
    float* zpad  = dinv + 524288;                  // 1,310,720 f
    float* w1pad = zpad + (size_t)N_GRAPHS * 80;   // 163,840 f
    float* whcat = w1pad + 80 * 2048;              // 32,768 f
    float* bh1p  = whcat + 128 * 256;              // 256 f
    int* counts  = (int*)(bh1p + 256);             // 500,000
    int* row_ptr = counts + N_NODES;               // 500,224
    int* cursor  = row_ptr + 500224;               // 500,000
    int* srcs    = cursor + N_NODES;               // 2,000,000
    int* bsum    = srcs + N_EDGES;                 // 256
    int* boff    = bsum + 256;                     // 256
    int* gstart  = boff + 256;                     // 16,640
    float* P     = bufB + 61902848;                // 2,097,152 f (tail of bufB)

    // conv activations / staging
    unsigned short* h_bf = (unsigned short*)bufA;  // [500k,128] u16 (bufA[0:32M f))
    unsigned short* r1   = (unsigned short*)bufB;  // [500k,128] u16 (bufB[0:32M f))
    unsigned short* wc1h = (unsigned short*)(bufA + 60000000);  // 24,576 u16
    unsigned short* wc1l = wc1h + 128 * KC1;                    // 24,576 u16

    // hi/lo activations & weights (timeline-disjoint reuse)
    unsigned short* z1h = (unsigned short*)bufB;                // after r1 dead
    unsigned short* z1l = (unsigned short*)(bufB + 16800000);
    unsigned short* z2h = (unsigned short*)bufA;                // after h_bf dead
    unsigned short* z2l = (unsigned short*)(bufA + 8400000);
    float* z3 = bufB + 34000000;
    unsigned short* w2th = (unsigned short*)(bufA + 33000000);  // written after h_bf dead
    unsigned short* w2tl = (unsigned short*)(bufA + 34100000);
    unsigned short* w3th = (unsigned short*)(bufA + 35200000);
    unsigned short* w3tl = (unsigned short*)(bufA + 35300000);
    float* ab = bufA + 36000000;

    // 1) CSR build + dinv + graph segments + P zero
    k_zero_counts<<<(N_NODES + 255) / 256, 256, 0, stream>>>(counts);
    k_hist<<<(N_EDGES + 255) / 256, 256, 0, stream>>>(edst, counts);
    k_scan_reduce<<<SCAN_NBLK, 256, 0, stream>>>(counts, bsum);
    k_scan_bsum<<<1, 256, 0, stream>>>(bsum, boff, row_ptr);
    k_scan_final<<<SCAN_NBLK, 256, 0, stream>>>(counts, boff, row_ptr, cursor, dinv);
    k_fill<<<(N_EDGES + 255) / 256, 256, 0, stream>>>(esrc, edst, cursor, srcs);
    k_gstart<<<(N_GRAPHS + 256) / 256, 256, 0, stream>>>(batch, gstart);
    k_zero_P<<<(N_GRAPHS * 128) / 256, 256, 0, stream>>>(P);

    // 2) conv1 via MFMA with fused x->bf16 staging ; Wc1 -> hi/lo
    k_wc1split<<<(128 * KC1 + 255) / 256, 256, 0, stream>>>(Wc1, wc1h, wc1l);
    k_mfma_conv1<<<(N_NODES + 127) / 128, 256, 0, stream>>>(x, wc1h, wc1l, h_bf);

    // gather+relu -> r1 (bf16, nontemporal store)
    k_gather1<<<(N_NODES * 64) / 256, 256, 0, stream>>>(h_bf, dinv, bc1, row_ptr, srcs, r1);

    // 3) fused conv2-agg + pool -> P (strip waves, register segment-sum, atomic flush)
    k_g2p<<<((N_NODES / STRIP) * 64 + 255) / 256, 256, 0, stream>>>(r1, dinv, row_ptr, srcs, batch, P);

    // weight transposes+splits
    k_tsplit<<<dim3(1024 / 64, 2048 / 64), 256, 0, stream>>>(W2, 2048, 1024, w2th, w2tl);
    k_tsplit<<<dim3(128 / 64, 1024 / 64), 256, 0, stream>>>(W3, 1024, 128, w3th, w3tl);

    k_zg<<<N_GRAPHS, 128, 0, stream>>>(P, gstart, Wc2, bc2, solv, zpad);

    // 4) MLP
    k_w1pad<<<(80 * 2048) / 256, 256, 0, stream>>>(W1, w1pad);
    k_whcat<<<(128 * 256) / 256, 256, 0, stream>>>(Wh1, whcat);
    k_bh1pad<<<1, 256, 0, stream>>>(bh1, bh1p);

    // W1 (fp32, K=80) -> z1 hi/lo
    k_gemm<true, 1><<<dim3(2048 / 128, N_GRAPHS / 128), 256, 0, stream>>>(
        zpad, w1pad, b1, nullptr, z1h, z1l, N_GRAPHS, 2048, 80);
    // W2 (split-bf16 MFMA, K=2048) -> z2 hi/lo
    k_mfma_split<1><<<(1024 / 128) * (N_GRAPHS / 128), 256, 0, stream>>>(
        z1h, z1l, w2th, w2tl, b2, nullptr, z2h, z2l, 1024, 2048);
    // W3 (split-bf16 MFMA, K=1024) -> z3 fp32
    k_mfma_split<0><<<(128 / 128) * (N_GRAPHS / 128), 256, 0, stream>>>(
        z2h, z2l, w3th, w3tl, b3, z3, nullptr, nullptr, 128, 1024);

    // 5) heads (fp32, K=128)
    k_gemm<true, 0><<<dim3(256 / 128, N_GRAPHS / 128), 256, 0, stream>>>(
        z3, whcat, bh1p, ab, nullptr, nullptr, N_GRAPHS, 256, 128);
    k_heads_out<<<(N_GRAPHS * 6 + 255) / 256, 256, 0, stream>>>(ab, Wh2, bh2, out);
}

// Round 9
// 1066.400 us; speedup vs baseline: 1.5853x; 1.0531x over previous
//
#include <hip/hip_runtime.h>

#define N_NODES 500000
#define N_EDGES 2000000
#define N_GRAPHS 16384
#define STRIP 16
#define KC1 192              // conv1 K padded 131 -> 192

#define SCAN_ELEMS 2048
#define SCAN_NBLK ((N_NODES + SCAN_ELEMS - 1) / SCAN_ELEMS)   // 245

typedef short bf16x8 __attribute__((ext_vector_type(8)));
typedef float f32x4 __attribute__((ext_vector_type(4)));
typedef unsigned short u16x8 __attribute__((ext_vector_type(8)));

__device__ __forceinline__ unsigned short f2bf_rne(float x) {
    unsigned int b = __float_as_uint(x);
    unsigned int r = (b + 0x7fffu + ((b >> 16) & 1u)) >> 16;
    return (unsigned short)r;
}
__device__ __forceinline__ float bf2f(unsigned short h) {
    return __uint_as_float(((unsigned int)h) << 16);
}
__device__ __forceinline__ void split_bf(float v, unsigned short& hi, unsigned short& lo) {
    hi = f2bf_rne(v);
    lo = f2bf_rne(v - bf2f(hi));
}

// ---------------- CSR build ----------------
__global__ __launch_bounds__(256) void k_zero_counts(int* counts) {
    int i = blockIdx.x * 256 + threadIdx.x;
    if (i < N_NODES) counts[i] = 0;
}
__global__ __launch_bounds__(256) void k_hist(const int* __restrict__ dst, int* __restrict__ counts) {
    int e = blockIdx.x * 256 + threadIdx.x;
    if (e < N_EDGES) atomicAdd(&counts[dst[e]], 1);
}
__global__ __launch_bounds__(256) void k_scan_reduce(const int* __restrict__ counts, int* __restrict__ bsum) {
    int b = blockIdx.x, t = threadIdx.x;
    int base_i = b * SCAN_ELEMS + t * 8;
    int s = 0;
    #pragma unroll
    for (int j = 0; j < 8; j++) { int i = base_i + j; if (i < N_NODES) s += counts[i]; }
    __shared__ int sh[256];
    sh[t] = s; __syncthreads();
    for (int off = 128; off > 0; off >>= 1) { if (t < off) sh[t] += sh[t + off]; __syncthreads(); }
    if (t == 0) bsum[b] = sh[0];
}
__global__ __launch_bounds__(256) void k_scan_bsum(const int* __restrict__ bsum, int* __restrict__ boff,
                                                   int* __restrict__ row_ptr) {
    __shared__ int sh[256];
    int t = threadIdx.x;
    int v = (t < SCAN_NBLK) ? bsum[t] : 0;
    sh[t] = v; __syncthreads();
    for (int off = 1; off < 256; off <<= 1) {
        int u = (t >= off) ? sh[t - off] : 0;
        __syncthreads();
        sh[t] += u; __syncthreads();
    }
    boff[t] = sh[t] - v;
    if (t == 255) row_ptr[N_NODES] = sh[255];
}
__global__ __launch_bounds__(256) void k_scan_final(const int* __restrict__ counts, const int* __restrict__ boff,
                                                    int* __restrict__ row_ptr, int* __restrict__ cursor,
                                                    float* __restrict__ dinv) {
    __shared__ int sh[256];
    int b = blockIdx.x, t = threadIdx.x;
    int base_i = b * SCAN_ELEMS + t * 8;
    int c[8]; int tsum = 0;
    #pragma unroll
    for (int j = 0; j < 8; j++) {
        int i = base_i + j;
        c[j] = (i < N_NODES) ? counts[i] : 0;
        tsum += c[j];
    }
    sh[t] = tsum; __syncthreads();
    for (int off = 1; off < 256; off <<= 1) {
        int u = (t >= off) ? sh[t - off] : 0;
        __syncthreads();
        sh[t] += u; __syncthreads();
    }
    int run = boff[b] + sh[t] - tsum;
    #pragma unroll
    for (int j = 0; j < 8; j++) {
        int i = base_i + j;
        if (i < N_NODES) {
            row_ptr[i] = run;
            cursor[i]  = run;
            dinv[i]    = rsqrtf((float)c[j] + 1.0f);
        }
        run += c[j];
    }
}
__global__ __launch_bounds__(256) void k_fill(const int* __restrict__ esrc, const int* __restrict__ edst,
                                              int* __restrict__ cursor, int* __restrict__ srcs) {
    int e = blockIdx.x * 256 + threadIdx.x;
    if (e >= N_EDGES) return;
    int d = edst[e];
    int pos = atomicAdd(&cursor[d], 1);
    srcs[pos] = esrc[e];
}
__global__ __launch_bounds__(256) void k_gstart(const int* __restrict__ batch, int* __restrict__ gstart) {
    int g = blockIdx.x * 256 + threadIdx.x;
    if (g > N_GRAPHS) return;
    if (g == N_GRAPHS) { gstart[g] = N_NODES; return; }
    int lo = 0, hi = N_NODES;
    while (lo < hi) { int mid = (lo + hi) >> 1; if (batch[mid] < g) lo = mid + 1; else hi = mid; }
    gstart[g] = lo;
}
__global__ __launch_bounds__(256) void k_zero_P(float* P) {
    int i = blockIdx.x * 256 + threadIdx.x;
    if (i < N_GRAPHS * 128) P[i] = 0.0f;
}

// ---------------- Wc1 [131][128] -> transposed padded hi/lo [128][192] ----------------
__global__ __launch_bounds__(256) void k_wc1split(const float* __restrict__ W,
                                                  unsigned short* __restrict__ Th,
                                                  unsigned short* __restrict__ Tl) {
    int idx = blockIdx.x * 256 + threadIdx.x;
    if (idx >= 128 * KC1) return;
    int c = idx / KC1, k = idx % KC1;
    float v = (k < 131) ? W[(size_t)k * 128 + c] : 0.0f;
    unsigned short hi, lo; split_bf(v, hi, lo);
    Th[idx] = hi; Tl[idx] = lo;
}

// ---------------- W1 [75..80][2048] -> transposed padded hi/lo [2048][128] ----------------
__global__ __launch_bounds__(256) void k_w1split(const float* __restrict__ W1,
                                                 unsigned short* __restrict__ Th,
                                                 unsigned short* __restrict__ Tl) {
    int idx = blockIdx.x * 256 + threadIdx.x;
    if (idx >= 2048 * 128) return;
    int n = idx >> 7, k = idx & 127;
    float v = (k < 75) ? W1[(size_t)k * 2048 + n] : 0.0f;
    unsigned short hi, lo; split_bf(v, hi, lo);
    Th[idx] = hi; Tl[idx] = lo;
}

// ---------------- Wh1 [6][128][32] -> concat transposed hi/lo [256][128] ----------------
__global__ __launch_bounds__(256) void k_whsplit(const float* __restrict__ Wh1,
                                                 unsigned short* __restrict__ Th,
                                                 unsigned short* __restrict__ Tl) {
    int idx = blockIdx.x * 256 + threadIdx.x;
    if (idx >= 256 * 128) return;
    int c = idx >> 7, f = idx & 127;
    float v = 0.0f;
    if (c < 192) v = Wh1[(c >> 5) * (128 * 32) + f * 32 + (c & 31)];
    unsigned short hi, lo; split_bf(v, hi, lo);
    Th[idx] = hi; Tl[idx] = lo;
}
__global__ __launch_bounds__(256) void k_bh1pad(const float* __restrict__ bh1, float* __restrict__ bh1pad) {
    int i = threadIdx.x;
    bh1pad[i] = (i < 192) ? bh1[i] : 0.0f;
}

// ---------------- conv1 A-tile reg loader (fp32 -> bf16, masked K tail) ----------------
__device__ __forceinline__ void conv1_loadA(const float* __restrict__ X, int bm, int w, int l,
                                            int koffg, int kt, u16x8* a_st) {
    const int k0 = kt * 64;
    #pragma unroll
    for (int i = 0; i < 8; i++) {
        int row = bm * 128 + w * 64 + i * 8 + (l >> 3);
        if (row >= N_NODES) row = N_NODES - 1;
        const float* src = X + (size_t)row * 131 + k0 + koffg;
        #pragma unroll
        for (int j = 0; j < 8; j++) {
            int k = k0 + koffg + j;
            a_st[i][j] = (k < 131) ? f2bf_rne(src[j]) : (unsigned short)0;
        }
    }
}

// ---------------- conv1 MFMA GEMM, fused x->bf16 staging + next-tile reg prefetch ----------------
__global__ __launch_bounds__(256) void k_mfma_conv1(const float* __restrict__ X,
                                                    const unsigned short* __restrict__ Bh,
                                                    const unsigned short* __restrict__ Bl,
                                                    unsigned short* __restrict__ C) {
    __shared__ short lds[24576];   // A: 0..8191, Bh: 8192..16383, Bl: 16384..24575
    const int tid = threadIdx.x;
    const int w = tid >> 6, l = tid & 63;
    const int bm = blockIdx.x;
    const int wm = w >> 1, wn = w & 1;
    const int lane15 = l & 15, lg = l >> 4, l7 = l & 7;
    const int koffg = ((l & 7) ^ ((l >> 3) & 7)) * 8;   // pre-swizzled col offset within 64-chunk
    f32x4 acc[4][4] = {};
    u16x8 a_st[8];
    if (w < 2) conv1_loadA(X, bm, w, l, koffg, 0, a_st);
    #pragma unroll
    for (int kt = 0; kt < 3; kt++) {
        const int k0 = kt * 64;
        __syncthreads();   // previous compute done; LDS safe to overwrite
        if (w < 2) {
            #pragma unroll
            for (int i = 0; i < 8; i++)
                *(u16x8*)&lds[w * 4096 + i * 512 + l * 8] = a_st[i];
            if (kt < 2) conv1_loadA(X, bm, w, l, koffg, kt + 1, a_st);  // flies under MFMA
        } else {
            const unsigned short* gB = (w == 2) ? Bh : Bl;
            #pragma unroll
            for (int i = 0; i < 16; i++) {
                int row = i * 8 + (l >> 3);
                const unsigned short* src = gB + (size_t)row * KC1 + k0 + koffg;
                __builtin_amdgcn_global_load_lds(
                    (const __attribute__((address_space(1))) unsigned int*)src,
                    (__attribute__((address_space(3))) unsigned int*)&lds[(w - 1) * 8192 + i * 512],
                    16, 0, 0);
            }
        }
        __syncthreads();   // staging visible
        #pragma unroll
        for (int kh = 0; kh < 2; kh++) {
            const int slot = ((kh * 4 + lg) ^ l7) * 8;
            bf16x8 af[4], bhf[4], blf[4];
            #pragma unroll
            for (int m = 0; m < 4; m++)
                af[m] = *(const bf16x8*)&lds[(wm * 64 + m * 16 + lane15) * 64 + slot];
            #pragma unroll
            for (int n = 0; n < 4; n++) {
                int si = (wn * 64 + n * 16 + lane15) * 64 + slot;
                bhf[n] = *(const bf16x8*)&lds[8192 + si];
                blf[n] = *(const bf16x8*)&lds[16384 + si];
            }
            #pragma unroll
            for (int m = 0; m < 4; m++)
                #pragma unroll
                for (int n = 0; n < 4; n++) {
                    acc[m][n] = __builtin_amdgcn_mfma_f32_16x16x32_bf16(af[m], bhf[n], acc[m][n], 0, 0, 0);
                    acc[m][n] = __builtin_amdgcn_mfma_f32_16x16x32_bf16(af[m], blf[n], acc[m][n], 0, 0, 0);
                }
        }
    }
    const size_t row_b = (size_t)bm * 128 + wm * 64 + lg * 4;
    const int col_b = wn * 64 + lane15;
    #pragma unroll
    for (int m = 0; m < 4; m++)
        #pragma unroll
        for (int n = 0; n < 4; n++) {
            int col = col_b + n * 16;
            #pragma unroll
            for (int j = 0; j < 4; j++) {
                size_t row = row_b + m * 16 + j;
                if (row < N_NODES)
                    C[row * 128 + col] = f2bf_rne(acc[m][n][j]);
            }
        }
}

// ---------------- conv1 gather (bf16 in, fp32 accum, relu, bf16 nt-out), edge loop x4 ----------------
__global__ __launch_bounds__(256) void k_gather1(const unsigned short* __restrict__ h,
                                                 const float* __restrict__ dinv,
                                                 const float* __restrict__ bias,
                                                 const int* __restrict__ row_ptr, const int* __restrict__ srcs,
                                                 unsigned short* __restrict__ r1) {
    int g = blockIdx.x * 256 + threadIdx.x;
    int n = g >> 6, lane = g & 63;
    if (n >= N_NODES) return;
    float dn = dinv[n];
    int c = lane * 2;
    unsigned int hv = *(const unsigned int*)(h + (size_t)n * 128 + c);
    float s2 = dn * dn;
    float a0 = fmaf(s2, bf2f((unsigned short)(hv & 0xffffu)), bias[c]);
    float a1 = fmaf(s2, bf2f((unsigned short)(hv >> 16)), bias[c + 1]);
    int e0 = row_ptr[n], e1 = row_ptr[n + 1];
    int e = e0;
    for (; e + 4 <= e1; e += 4) {
        int sA = srcs[e], sB = srcs[e + 1], sC = srcs[e + 2], sD = srcs[e + 3];
        float nA = dinv[sA] * dn, nB = dinv[sB] * dn, nC = dinv[sC] * dn, nD = dinv[sD] * dn;
        unsigned int hA = *(const unsigned int*)(h + (size_t)sA * 128 + c);
        unsigned int hB = *(const unsigned int*)(h + (size_t)sB * 128 + c);
        unsigned int hC = *(const unsigned int*)(h + (size_t)sC * 128 + c);
        unsigned int hD = *(const unsigned int*)(h + (size_t)sD * 128 + c);
        a0 = fmaf(nA, bf2f((unsigned short)(hA & 0xffffu)), a0);
        a1 = fmaf(nA, bf2f((unsigned short)(hA >> 16)), a1);
        a0 = fmaf(nB, bf2f((unsigned short)(hB & 0xffffu)), a0);
        a1 = fmaf(nB, bf2f((unsigned short)(hB >> 16)), a1);
        a0 = fmaf(nC, bf2f((unsigned short)(hC & 0xffffu)), a0);
        a1 = fmaf(nC, bf2f((unsigned short)(hC >> 16)), a1);
        a0 = fmaf(nD, bf2f((unsigned short)(hD & 0xffffu)), a0);
        a1 = fmaf(nD, bf2f((unsigned short)(hD >> 16)), a1);
    }
    for (; e < e1; e++) {
        int sA = srcs[e];
        float nA = dinv[sA] * dn;
        unsigned int hA = *(const unsigned int*)(h + (size_t)sA * 128 + c);
        a0 = fmaf(nA, bf2f((unsigned short)(hA & 0xffffu)), a0);
        a1 = fmaf(nA, bf2f((unsigned short)(hA >> 16)), a1);
    }
    a0 = fmaxf(a0, 0.0f);
    a1 = fmaxf(a1, 0.0f);
    unsigned int o = (unsigned int)f2bf_rne(a0) | ((unsigned int)f2bf_rne(a1) << 16);
    __builtin_nontemporal_store(o, (unsigned int*)(r1 + (size_t)n * 128 + c));
}

// ---------------- fused conv2-agg + pool: wave-per-strip, register segment-sum, atomic flush ----------------
__global__ __launch_bounds__(256) void k_g2p(const unsigned short* __restrict__ r1,
                                             const float* __restrict__ dinv,
                                             const int* __restrict__ row_ptr, const int* __restrict__ srcs,
                                             const int* __restrict__ batch,
                                             float* __restrict__ P) {
    int gw = (blockIdx.x * 256 + threadIdx.x) >> 6;
    int lane = threadIdx.x & 63;
    if (gw >= N_NODES / STRIP) return;
    int n0 = gw * STRIP;
    int c = lane * 2;
    float a0 = 0.0f, a1 = 0.0f;
    int cur_g = batch[n0];
    for (int n = n0; n < n0 + STRIP; n++) {
        int bg = batch[n];
        if (bg != cur_g) {
            atomicAdd(&P[(size_t)cur_g * 128 + c], a0);
            atomicAdd(&P[(size_t)cur_g * 128 + c + 1], a1);
            a0 = a1 = 0.0f;
            cur_g = bg;
        }
        float dn = dinv[n];
        float s2 = dn * dn;
        unsigned int hv = *(const unsigned int*)(r1 + (size_t)n * 128 + c);
        a0 = fmaf(s2, bf2f((unsigned short)(hv & 0xffffu)), a0);
        a1 = fmaf(s2, bf2f((unsigned short)(hv >> 16)), a1);
        int e0 = row_ptr[n], e1 = row_ptr[n + 1];
        int e = e0;
        for (; e + 4 <= e1; e += 4) {
            int sA = srcs[e], sB = srcs[e + 1], sC = srcs[e + 2], sD = srcs[e + 3];
            float nA = dinv[sA] * dn, nB = dinv[sB] * dn, nC = dinv[sC] * dn, nD = dinv[sD] * dn;
            unsigned int hA = *(const unsigned int*)(r1 + (size_t)sA * 128 + c);
            unsigned int hB = *(const unsigned int*)(r1 + (size_t)sB * 128 + c);
            unsigned int hC = *(const unsigned int*)(r1 + (size_t)sC * 128 + c);
            unsigned int hD = *(const unsigned int*)(r1 + (size_t)sD * 128 + c);
            a0 = fmaf(nA, bf2f((unsigned short)(hA & 0xffffu)), a0);
            a1 = fmaf(nA, bf2f((unsigned short)(hA >> 16)), a1);
            a0 = fmaf(nB, bf2f((unsigned short)(hB & 0xffffu)), a0);
            a1 = fmaf(nB, bf2f((unsigned short)(hB >> 16)), a1);
            a0 = fmaf(nC, bf2f((unsigned short)(hC & 0xffffu)), a0);
            a1 = fmaf(nC, bf2f((unsigned short)(hC >> 16)), a1);
            a0 = fmaf(nD, bf2f((unsigned short)(hD & 0xffffu)), a0);
            a1 = fmaf(nD, bf2f((unsigned short)(hD >> 16)), a1);
        }
        for (; e < e1; e++) {
            int sA = srcs[e];
            float nA = dinv[sA] * dn;
            unsigned int hA = *(const unsigned int*)(r1 + (size_t)sA * 128 + c);
            a0 = fmaf(nA, bf2f((unsigned short)(hA & 0xffffu)), a0);
            a1 = fmaf(nA, bf2f((unsigned short)(hA >> 16)), a1);
        }
    }
    atomicAdd(&P[(size_t)cur_g * 128 + c], a0);
    atomicAdd(&P[(size_t)cur_g * 128 + c + 1], a1);
}

// ---------------- z0 build (hi/lo bf16, K padded to 128): cols 0..63 = P@Wc2 + cnt*bc2 ; 64..74 = solv ----------------
__global__ __launch_bounds__(128) void k_zg(const float* __restrict__ P, const int* __restrict__ gstart,
                                            const float* __restrict__ Wc2, const float* __restrict__ bc2,
                                            const float* __restrict__ solv,
                                            unsigned short* __restrict__ z0h, unsigned short* __restrict__ z0l) {
    int g = blockIdx.x; int c = threadIdx.x;   // c in [0,128)
    float v = 0.0f;
    if (c < 64) {
        const float* pr = P + (size_t)g * 128;
        float s = 0.0f;
        #pragma unroll 8
        for (int k = 0; k < 128; k++) s = fmaf(pr[k], Wc2[k * 64 + c], s);
        v = s + (float)(gstart[g + 1] - gstart[g]) * bc2[c];
    } else if (c < 75) {
        v = solv[g * 11 + (c - 64)];
    }
    unsigned short hi, lo; split_bf(v, hi, lo);
    z0h[(size_t)g * 128 + c] = hi;
    z0l[(size_t)g * 128 + c] = lo;
}

// ---------------- transpose + hi/lo split (64-multiple dims) ----------------
__global__ __launch_bounds__(256) void k_tsplit(const float* __restrict__ W, int R, int C,
                                                unsigned short* __restrict__ Th, unsigned short* __restrict__ Tl) {
    __shared__ float tile[64][65];
    int cb = blockIdx.x * 64, rb = blockIdx.y * 64;
    int tc = threadIdx.x & 63, tr4 = threadIdx.x >> 6;
    #pragma unroll 4
    for (int i = 0; i < 16; i++) {
        int r = tr4 + i * 4;
        tile[r][tc] = W[(size_t)(rb + r) * C + cb + tc];
    }
    __syncthreads();
    #pragma unroll 4
    for (int i = 0; i < 16; i++) {
        int r = tr4 + i * 4;
        float v = tile[tc][r];
        unsigned short hi, lo; split_bf(v, hi, lo);
        size_t o = (size_t)(cb + r) * R + rb + tc;
        Th[o] = hi; Tl[o] = lo;
    }
}

// ---------------- split-bf16 MFMA GEMM: C[M,N] = relu(A @ B^T + bias) ----------------
template<int OMODE>  // 0: fp32 out, 1: bf16 hi/lo out
__global__ __launch_bounds__(256) void k_mfma_split(
        const unsigned short* __restrict__ Ah, const unsigned short* __restrict__ Al,
        const unsigned short* __restrict__ Bh, const unsigned short* __restrict__ Bl,
        const float* __restrict__ bias,
        float* __restrict__ C, unsigned short* __restrict__ Ch, unsigned short* __restrict__ Cl,
        int N, int K) {
    __shared__ short lds[32768];   // 64 KB: 4 tiles [128 rows][64 bf16], swizzled
    const int tid = threadIdx.x;
    const int w = tid >> 6, l = tid & 63;
    const int id = blockIdx.x;
    const int bm = id & 127;
    const int bn = id >> 7;
    const unsigned short* gmat = (w == 0) ? Ah : (w == 1) ? Al : (w == 2) ? Bh : Bl;
    const size_t grow0 = (size_t)((w < 2) ? bm : bn) * 128 + (l >> 3);
    const int koffg = ((l & 7) ^ ((l >> 3) & 7)) * 8;
    const int ldsw = w * 8192;
    const int wm = w >> 1, wn = w & 1;
    const int lane15 = l & 15, lg = l >> 4, l7 = l & 7;
    f32x4 acc[4][4] = {};
    const int NK = K >> 6;
    for (int kt = 0; kt < NK; kt++) {
        const int k0 = kt << 6;
        __syncthreads();
        #pragma unroll
        for (int i = 0; i < 16; i++) {
            const unsigned short* src = gmat + (grow0 + (size_t)i * 8) * (size_t)K + k0 + koffg;
            __builtin_amdgcn_global_load_lds(
                (const __attribute__((address_space(1))) unsigned int*)src,
                (__attribute__((address_space(3))) unsigned int*)&lds[ldsw + i * 512],
                16, 0, 0);
        }
        __syncthreads();
        #pragma unroll
        for (int kh = 0; kh < 2; kh++) {
            const int slot = ((kh * 4 + lg) ^ l7) * 8;
            bf16x8 ahf[4], alf[4], bhf[4], blf[4];
            #pragma unroll
            for (int m = 0; m < 4; m++) {
                int si = (wm * 64 + m * 16 + lane15) * 64 + slot;
                ahf[m] = *(const bf16x8*)&lds[si];
                alf[m] = *(const bf16x8*)&lds[8192 + si];
            }
            #pragma unroll
            for (int n = 0; n < 4; n++) {
                int si = (wn * 64 + n * 16 + lane15) * 64 + slot;
                bhf[n] = *(const bf16x8*)&lds[16384 + si];
                blf[n] = *(const bf16x8*)&lds[24576 + si];
            }
            #pragma unroll
            for (int m = 0; m < 4; m++)
                #pragma unroll
                for (int n = 0; n < 4; n++) {
                    acc[m][n] = __builtin_amdgcn_mfma_f32_16x16x32_bf16(ahf[m], bhf[n], acc[m][n], 0, 0, 0);
                    acc[m][n] = __builtin_amdgcn_mfma_f32_16x16x32_bf16(ahf[m], blf[n], acc[m][n], 0, 0, 0);
                    acc[m][n] = __builtin_amdgcn_mfma_f32_16x16x32_bf16(alf[m], bhf[n], acc[m][n], 0, 0, 0);
                }
        }
    }
    const int row_b = bm * 128 + wm * 64 + lg * 4;
    const int col_b = bn * 128 + wn * 64 + lane15;
    #pragma unroll
    for (int m = 0; m < 4; m++)
        #pragma unroll
        for (int n = 0; n < 4; n++) {
            int col = col_b + n * 16;
            float bv = bias[col];
            #pragma unroll
            for (int j = 0; j < 4; j++) {
                int row = row_b + m * 16 + j;
                float v = fmaxf(acc[m][n][j] + bv, 0.0f);
                size_t o = (size_t)row * N + col;
                if (OMODE == 0) {
                    C[o] = v;
                } else {
                    unsigned short hi, lo; split_bf(v, hi, lo);
                    Ch[o] = hi; Cl[o] = lo;
                }
            }
        }
}

// ---------------- final heads reduce ----------------
__global__ __launch_bounds__(256) void k_heads_out(const float* __restrict__ a,
                                                   const float* __restrict__ Wh2,
                                                   const float* __restrict__ bh2,
                                                   float* __restrict__ out) {
    int i = blockIdx.x * 256 + threadIdx.x;
    if (i >= N_GRAPHS * 6) return;
    int g = i / 6, h = i % 6;
    const float* ap = a + (size_t)g * 256 + h * 32;
    const float* wp = Wh2 + h * 32;
    float s = 0.0f;
    #pragma unroll
    for (int k = 0; k < 32; k++) s = fmaf(ap[k], wp[k], s);
    out[i] = s + bh2[h];
}

extern "C" void kernel_launch(void* const* d_in, const int* in_sizes, int n_in,
                              void* d_out, int out_size, void* d_ws, size_t ws_size,
                              hipStream_t stream) {
    const float* x    = (const float*)d_in[0];
    const int*   esrc = (const int*)d_in[1];
    const int*   edst = (const int*)d_in[2];
    const int*   batch= (const int*)d_in[3];
    const float* solv = (const float*)d_in[4];
    const float* Wc1  = (const float*)d_in[5];
    const float* bc1  = (const float*)d_in[6];
    const float* Wc2  = (const float*)d_in[7];
    const float* bc2  = (const float*)d_in[8];
    const float* W1   = (const float*)d_in[9];
    const float* b1   = (const float*)d_in[10];
    const float* W2   = (const float*)d_in[11];
    const float* b2   = (const float*)d_in[12];
    const float* W3   = (const float*)d_in[13];
    const float* b3   = (const float*)d_in[14];
    const float* Wh1  = (const float*)d_in[15];
    const float* bh1  = (const float*)d_in[16];
    const float* Wh2  = (const float*)d_in[17];
    const float* bh2  = (const float*)d_in[18];
    float* out = (float*)d_out;

    // workspace layout (floats)
    float* ws    = (float*)d_ws;
    float* bufA  = ws;                             // 64,000,000 f
    float* bufB  = bufA + 64000000;                // 64,000,000 f
    float* dinv  = bufB + 64000000;                // 524,288 f
    float* bh1p  = dinv + 524288;                  // 256 f
    int* counts  = (int*)(bh1p + 256);             // 500,000
    int* row_ptr = counts + N_NODES;               // 500,224
    int* cursor  = row_ptr + 500224;               // 500,000
    int* srcs    = cursor + N_NODES;               // 2,000,000
    int* bsum    = srcs + N_EDGES;                 // 256
    int* boff    = bsum + 256;                     // 256
    int* gstart  = boff + 256;                     // 16,640
    float* P     = bufB + 61902848;                // 2,097,152 f (tail of bufB)

    // conv activations / staging
    unsigned short* h_bf = (unsigned short*)bufA;  // [500k,128] u16 (bufA[0:32M f))
    unsigned short* r1   = (unsigned short*)bufB;  // [500k,128] u16 (bufB[0:32M f))
    unsigned short* wc1h = (unsigned short*)(bufA + 60000000);  // 24,576 u16
    unsigned short* wc1l = wc1h + 128 * KC1;                    // 24,576 u16

    // MLP hi/lo activations & weights (timeline-disjoint reuse)
    unsigned short* z1h  = (unsigned short*)bufB;               // after r1 dead
    unsigned short* z1l  = (unsigned short*)(bufB + 16800000);
    unsigned short* z2h  = (unsigned short*)bufA;               // after h_bf dead
    unsigned short* z2l  = (unsigned short*)(bufA + 8400000);
    unsigned short* z3h  = (unsigned short*)(bufB + 34000000);  // 2.1M u16
    unsigned short* z3l  = (unsigned short*)(bufB + 35100000);
    unsigned short* z0h  = (unsigned short*)(bufA + 20000000);  // [16384,128] u16
    unsigned short* z0l  = (unsigned short*)(bufA + 21100000);
    unsigned short* w1th = (unsigned short*)(bufA + 22200000);  // [2048,128] u16
    unsigned short* w1tl = (unsigned short*)(bufA + 22400000);
    unsigned short* whh  = (unsigned short*)(bufA + 22600000);  // [256,128] u16
    unsigned short* whl  = (unsigned short*)(bufA + 22700000);
    unsigned short* w2th = (unsigned short*)(bufA + 33000000);  // [1024,2048] u16
    unsigned short* w2tl = (unsigned short*)(bufA + 34100000);
    unsigned short* w3th = (unsigned short*)(bufA + 35200000);  // [128,1024] u16
    unsigned short* w3tl = (unsigned short*)(bufA + 35300000);
    float* ab = bufA + 36000000;                                // [16384,256] f

    // 1) CSR build + dinv + graph segments + P zero
    k_zero_counts<<<(N_NODES + 255) / 256, 256, 0, stream>>>(counts);
    k_hist<<<(N_EDGES + 255) / 256, 256, 0, stream>>>(edst, counts);
    k_scan_reduce<<<SCAN_NBLK, 256, 0, stream>>>(counts, bsum);
    k_scan_bsum<<<1, 256, 0, stream>>>(bsum, boff, row_ptr);
    k_scan_final<<<SCAN_NBLK, 256, 0, stream>>>(counts, boff, row_ptr, cursor, dinv);
    k_fill<<<(N_EDGES + 255) / 256, 256, 0, stream>>>(esrc, edst, cursor, srcs);
    k_gstart<<<(N_GRAPHS + 256) / 256, 256, 0, stream>>>(batch, gstart);
    k_zero_P<<<(N_GRAPHS * 128) / 256, 256, 0, stream>>>(P);

    // 2) conv1 via MFMA (fused x->bf16 staging, A prefetch) ; Wc1 -> hi/lo
    k_wc1split<<<(128 * KC1 + 255) / 256, 256, 0, stream>>>(Wc1, wc1h, wc1l);
    k_mfma_conv1<<<(N_NODES + 127) / 128, 256, 0, stream>>>(x, wc1h, wc1l, h_bf);

    // gather+relu -> r1 (bf16, nontemporal store)
    k_gather1<<<(N_NODES * 64) / 256, 256, 0, stream>>>(h_bf, dinv, bc1, row_ptr, srcs, r1);

    // 3) fused conv2-agg + pool -> P
    k_g2p<<<((N_NODES / STRIP) * 64 + 255) / 256, 256, 0, stream>>>(r1, dinv, row_ptr, srcs, batch, P);

    // weight transposes+splits (h_bf region dead after gather1)
    k_tsplit<<<dim3(1024 / 64, 2048 / 64), 256, 0, stream>>>(W2, 2048, 1024, w2th, w2tl);
    k_tsplit<<<dim3(128 / 64, 1024 / 64), 256, 0, stream>>>(W3, 1024, 128, w3th, w3tl);
    k_w1split<<<(2048 * 128) / 256, 256, 0, stream>>>(W1, w1th, w1tl);
    k_whsplit<<<(256 * 128) / 256, 256, 0, stream>>>(Wh1, whh, whl);
    k_bh1pad<<<1, 256, 0, stream>>>(bh1, bh1p);

    // z0 = [pool@Wc2 + cnt*bc2 | solv | 0] as hi/lo bf16, K padded to 128
    k_zg<<<N_GRAPHS, 128, 0, stream>>>(P, gstart, Wc2, bc2, solv, z0h, z0l);

    // 4) MLP — all split-bf16 MFMA
    // W1 (K=128 padded) -> z1 hi/lo
    k_mfma_split<1><<<(2048 / 128) * (N_GRAPHS / 128), 256, 0, stream>>>(
        z0h, z0l, w1th, w1tl, b1, nullptr, z1h, z1l, 2048, 128);
    // W2 (K=2048) -> z2 hi/lo
    k_mfma_split<1><<<(1024 / 128) * (N_GRAPHS / 128), 256, 0, stream>>>(
        z1h, z1l, w2th, w2tl, b2, nullptr, z2h, z2l, 1024, 2048);
    // W3 (K=1024) -> z3 hi/lo
    k_mfma_split<1><<<(128 / 128) * (N_GRAPHS / 128), 256, 0, stream>>>(
        z2h, z2l, w3th, w3tl, b3, nullptr, z3h, z3l, 128, 1024);
    // heads layer 1 (K=128) -> ab fp32
    k_mfma_split<0><<<(256 / 128) * (N_GRAPHS / 128), 256, 0, stream>>>(
        z3h, z3l, whh, whl, bh1p, ab, nullptr, nullptr, 256, 128);

    // 5) final heads reduce
    k_heads_out<<<(N_GRAPHS * 6 + 255) / 256, 256, 0, stream>>>(ab, Wh2, bh2, out);
}

// Round 10
// 1065.787 us; speedup vs baseline: 1.5862x; 1.0006x over previous
//
#include <hip/hip_runtime.h>

#define N_NODES 500000
#define N_EDGES 2000000
#define N_GRAPHS 16384
#define STRIP 16
#define KC1 192              // conv1 K padded 131 -> 192

#define SCAN_ELEMS 2048
#define SCAN_NBLK ((N_NODES + SCAN_ELEMS - 1) / SCAN_ELEMS)   // 245

typedef short bf16x8 __attribute__((ext_vector_type(8)));
typedef float f32x4 __attribute__((ext_vector_type(4)));
typedef unsigned short u16x8 __attribute__((ext_vector_type(8)));

__device__ __forceinline__ unsigned short f2bf_rne(float x) {
    unsigned int b = __float_as_uint(x);
    unsigned int r = (b + 0x7fffu + ((b >> 16) & 1u)) >> 16;
    return (unsigned short)r;
}
__device__ __forceinline__ float bf2f(unsigned short h) {
    return __uint_as_float(((unsigned int)h) << 16);
}
__device__ __forceinline__ void split_bf(float v, unsigned short& hi, unsigned short& lo) {
    hi = f2bf_rne(v);
    lo = f2bf_rne(v - bf2f(hi));
}

// ---------------- CSR build ----------------
__global__ __launch_bounds__(256) void k_zero_counts(int* counts) {
    int i = blockIdx.x * 256 + threadIdx.x;
    if (i < N_NODES) counts[i] = 0;
}
__global__ __launch_bounds__(256) void k_hist(const int* __restrict__ dst, int* __restrict__ counts) {
    int e = blockIdx.x * 256 + threadIdx.x;
    if (e < N_EDGES) atomicAdd(&counts[dst[e]], 1);
}
__global__ __launch_bounds__(256) void k_scan_reduce(const int* __restrict__ counts, int* __restrict__ bsum) {
    int b = blockIdx.x, t = threadIdx.x;
    int base_i = b * SCAN_ELEMS + t * 8;
    int s = 0;
    #pragma unroll
    for (int j = 0; j < 8; j++) { int i = base_i + j; if (i < N_NODES) s += counts[i]; }
    __shared__ int sh[256];
    sh[t] = s; __syncthreads();
    for (int off = 128; off > 0; off >>= 1) { if (t < off) sh[t] += sh[t + off]; __syncthreads(); }
    if (t == 0) bsum[b] = sh[0];
}
__global__ __launch_bounds__(256) void k_scan_bsum(const int* __restrict__ bsum, int* __restrict__ boff,
                                                   int* __restrict__ row_ptr) {
    __shared__ int sh[256];
    int t = threadIdx.x;
    int v = (t < SCAN_NBLK) ? bsum[t] : 0;
    sh[t] = v; __syncthreads();
    for (int off = 1; off < 256; off <<= 1) {
        int u = (t >= off) ? sh[t - off] : 0;
        __syncthreads();
        sh[t] += u; __syncthreads();
    }
    boff[t] = sh[t] - v;
    if (t == 255) row_ptr[N_NODES] = sh[255];
}
__global__ __launch_bounds__(256) void k_scan_final(const int* __restrict__ counts, const int* __restrict__ boff,
                                                    int* __restrict__ row_ptr, int* __restrict__ cursor,
                                                    float* __restrict__ dinv) {
    __shared__ int sh[256];
    int b = blockIdx.x, t = threadIdx.x;
    int base_i = b * SCAN_ELEMS + t * 8;
    int c[8]; int tsum = 0;
    #pragma unroll
    for (int j = 0; j < 8; j++) {
        int i = base_i + j;
        c[j] = (i < N_NODES) ? counts[i] : 0;
        tsum += c[j];
    }
    sh[t] = tsum; __syncthreads();
    for (int off = 1; off < 256; off <<= 1) {
        int u = (t >= off) ? sh[t - off] : 0;
        __syncthreads();
        sh[t] += u; __syncthreads();
    }
    int run = boff[b] + sh[t] - tsum;
    #pragma unroll
    for (int j = 0; j < 8; j++) {
        int i = base_i + j;
        if (i < N_NODES) {
            row_ptr[i] = run;
            cursor[i]  = run;
            dinv[i]    = rsqrtf((float)c[j] + 1.0f);
        }
        run += c[j];
    }
}
__global__ __launch_bounds__(256) void k_fill(const int* __restrict__ esrc, const int* __restrict__ edst,
                                              int* __restrict__ cursor, int* __restrict__ srcs) {
    int e = blockIdx.x * 256 + threadIdx.x;
    if (e >= N_EDGES) return;
    int d = edst[e];
    int pos = atomicAdd(&cursor[d], 1);
    srcs[pos] = esrc[e];
}
__global__ __launch_bounds__(256) void k_gstart(const int* __restrict__ batch, int* __restrict__ gstart) {
    int g = blockIdx.x * 256 + threadIdx.x;
    if (g > N_GRAPHS) return;
    if (g == N_GRAPHS) { gstart[g] = N_NODES; return; }
    int lo = 0, hi = N_NODES;
    while (lo < hi) { int mid = (lo + hi) >> 1; if (batch[mid] < g) lo = mid + 1; else hi = mid; }
    gstart[g] = lo;
}
__global__ __launch_bounds__(256) void k_zero_P(float* P) {
    int i = blockIdx.x * 256 + threadIdx.x;
    if (i < N_GRAPHS * 128) P[i] = 0.0f;
}

// ---------------- Wc1 [131][128] -> transposed padded hi/lo [128][192] ----------------
__global__ __launch_bounds__(256) void k_wc1split(const float* __restrict__ W,
                                                  unsigned short* __restrict__ Th,
                                                  unsigned short* __restrict__ Tl) {
    int idx = blockIdx.x * 256 + threadIdx.x;
    if (idx >= 128 * KC1) return;
    int c = idx / KC1, k = idx % KC1;
    float v = (k < 131) ? W[(size_t)k * 128 + c] : 0.0f;
    unsigned short hi, lo; split_bf(v, hi, lo);
    Th[idx] = hi; Tl[idx] = lo;
}

// ---------------- W1 [75..80][2048] -> transposed padded hi/lo [2048][128] ----------------
__global__ __launch_bounds__(256) void k_w1split(const float* __restrict__ W1,
                                                 unsigned short* __restrict__ Th,
                                                 unsigned short* __restrict__ Tl) {
    int idx = blockIdx.x * 256 + threadIdx.x;
    if (idx >= 2048 * 128) return;
    int n = idx >> 7, k = idx & 127;
    float v = (k < 75) ? W1[(size_t)k * 2048 + n] : 0.0f;
    unsigned short hi, lo; split_bf(v, hi, lo);
    Th[idx] = hi; Tl[idx] = lo;
}

// ---------------- Wh1 [6][128][32] -> concat transposed hi/lo [256][128] ----------------
__global__ __launch_bounds__(256) void k_whsplit(const float* __restrict__ Wh1,
                                                 unsigned short* __restrict__ Th,
                                                 unsigned short* __restrict__ Tl) {
    int idx = blockIdx.x * 256 + threadIdx.x;
    if (idx >= 256 * 128) return;
    int c = idx >> 7, f = idx & 127;
    float v = 0.0f;
    if (c < 192) v = Wh1[(c >> 5) * (128 * 32) + f * 32 + (c & 31)];
    unsigned short hi, lo; split_bf(v, hi, lo);
    Th[idx] = hi; Tl[idx] = lo;
}
__global__ __launch_bounds__(256) void k_bh1pad(const float* __restrict__ bh1, float* __restrict__ bh1pad) {
    int i = threadIdx.x;
    bh1pad[i] = (i < 192) ? bh1[i] : 0.0f;
}

// ---------------- conv1 A-tile reg loader (fp32 -> bf16, masked K tail) ----------------
__device__ __forceinline__ void conv1_loadA(const float* __restrict__ X, int bm, int w, int l,
                                            int koffg, int kt, u16x8* a_st) {
    const int k0 = kt * 64;
    #pragma unroll
    for (int i = 0; i < 8; i++) {
        int row = bm * 128 + w * 64 + i * 8 + (l >> 3);
        if (row >= N_NODES) row = N_NODES - 1;
        const float* src = X + (size_t)row * 131 + k0 + koffg;
        #pragma unroll
        for (int j = 0; j < 8; j++) {
            int k = k0 + koffg + j;
            a_st[i][j] = (k < 131) ? f2bf_rne(src[j]) : (unsigned short)0;
        }
    }
}

// ---------------- conv1 MFMA GEMM, fused x->bf16 staging + next-tile reg prefetch ----------------
__global__ __launch_bounds__(256) void k_mfma_conv1(const float* __restrict__ X,
                                                    const unsigned short* __restrict__ Bh,
                                                    const unsigned short* __restrict__ Bl,
                                                    unsigned short* __restrict__ C) {
    __shared__ short lds[24576];   // A: 0..8191, Bh: 8192..16383, Bl: 16384..24575
    const int tid = threadIdx.x;
    const int w = tid >> 6, l = tid & 63;
    const int bm = blockIdx.x;
    const int wm = w >> 1, wn = w & 1;
    const int lane15 = l & 15, lg = l >> 4, l7 = l & 7;
    const int koffg = ((l & 7) ^ ((l >> 3) & 7)) * 8;   // pre-swizzled col offset within 64-chunk
    f32x4 acc[4][4] = {};
    u16x8 a_st[8];
    if (w < 2) conv1_loadA(X, bm, w, l, koffg, 0, a_st);
    #pragma unroll
    for (int kt = 0; kt < 3; kt++) {
        const int k0 = kt * 64;
        __syncthreads();   // previous compute done; LDS safe to overwrite
        if (w < 2) {
            #pragma unroll
            for (int i = 0; i < 8; i++)
                *(u16x8*)&lds[w * 4096 + i * 512 + l * 8] = a_st[i];
            if (kt < 2) conv1_loadA(X, bm, w, l, koffg, kt + 1, a_st);  // flies under MFMA
        } else {
            const unsigned short* gB = (w == 2) ? Bh : Bl;
            #pragma unroll
            for (int i = 0; i < 16; i++) {
                int row = i * 8 + (l >> 3);
                const unsigned short* src = gB + (size_t)row * KC1 + k0 + koffg;
                __builtin_amdgcn_global_load_lds(
                    (const __attribute__((address_space(1))) unsigned int*)src,
                    (__attribute__((address_space(3))) unsigned int*)&lds[(w - 1) * 8192 + i * 512],
                    16, 0, 0);
            }
        }
        __syncthreads();   // staging visible
        #pragma unroll
        for (int kh = 0; kh < 2; kh++) {
            const int slot = ((kh * 4 + lg) ^ l7) * 8;
            bf16x8 af[4], bhf[4], blf[4];
            #pragma unroll
            for (int m = 0; m < 4; m++)
                af[m] = *(const bf16x8*)&lds[(wm * 64 + m * 16 + lane15) * 64 + slot];
            #pragma unroll
            for (int n = 0; n < 4; n++) {
                int si = (wn * 64 + n * 16 + lane15) * 64 + slot;
                bhf[n] = *(const bf16x8*)&lds[8192 + si];
                blf[n] = *(const bf16x8*)&lds[16384 + si];
            }
            #pragma unroll
            for (int m = 0; m < 4; m++)
                #pragma unroll
                for (int n = 0; n < 4; n++) {
                    acc[m][n] = __builtin_amdgcn_mfma_f32_16x16x32_bf16(af[m], bhf[n], acc[m][n], 0, 0, 0);
                    acc[m][n] = __builtin_amdgcn_mfma_f32_16x16x32_bf16(af[m], blf[n], acc[m][n], 0, 0, 0);
                }
        }
    }
    const size_t row_b = (size_t)bm * 128 + wm * 64 + lg * 4;
    const int col_b = wn * 64 + lane15;
    #pragma unroll
    for (int m = 0; m < 4; m++)
        #pragma unroll
        for (int n = 0; n < 4; n++) {
            int col = col_b + n * 16;
            #pragma unroll
            for (int j = 0; j < 4; j++) {
                size_t row = row_b + m * 16 + j;
                if (row < N_NODES)
                    C[row * 128 + col] = f2bf_rne(acc[m][n][j]);
            }
        }
}

// ---------------- conv1 gather (bf16 in, fp32 accum, relu, bf16 nt-out), edge loop x4 ----------------
__global__ __launch_bounds__(256) void k_gather1(const unsigned short* __restrict__ h,
                                                 const float* __restrict__ dinv,
                                                 const float* __restrict__ bias,
                                                 const int* __restrict__ row_ptr, const int* __restrict__ srcs,
                                                 unsigned short* __restrict__ r1) {
    int g = blockIdx.x * 256 + threadIdx.x;
    int n = g >> 6, lane = g & 63;
    if (n >= N_NODES) return;
    float dn = dinv[n];
    int c = lane * 2;
    unsigned int hv = *(const unsigned int*)(h + (size_t)n * 128 + c);
    float s2 = dn * dn;
    float a0 = fmaf(s2, bf2f((unsigned short)(hv & 0xffffu)), bias[c]);
    float a1 = fmaf(s2, bf2f((unsigned short)(hv >> 16)), bias[c + 1]);
    int e0 = row_ptr[n], e1 = row_ptr[n + 1];
    int e = e0;
    for (; e + 4 <= e1; e += 4) {
        int sA = srcs[e], sB = srcs[e + 1], sC = srcs[e + 2], sD = srcs[e + 3];
        float nA = dinv[sA] * dn, nB = dinv[sB] * dn, nC = dinv[sC] * dn, nD = dinv[sD] * dn;
        unsigned int hA = *(const unsigned int*)(h + (size_t)sA * 128 + c);
        unsigned int hB = *(const unsigned int*)(h + (size_t)sB * 128 + c);
        unsigned int hC = *(const unsigned int*)(h + (size_t)sC * 128 + c);
        unsigned int hD = *(const unsigned int*)(h + (size_t)sD * 128 + c);
        a0 = fmaf(nA, bf2f((unsigned short)(hA & 0xffffu)), a0);
        a1 = fmaf(nA, bf2f((unsigned short)(hA >> 16)), a1);
        a0 = fmaf(nB, bf2f((unsigned short)(hB & 0xffffu)), a0);
        a1 = fmaf(nB, bf2f((unsigned short)(hB >> 16)), a1);
        a0 = fmaf(nC, bf2f((unsigned short)(hC & 0xffffu)), a0);
        a1 = fmaf(nC, bf2f((unsigned short)(hC >> 16)), a1);
        a0 = fmaf(nD, bf2f((unsigned short)(hD & 0xffffu)), a0);
        a1 = fmaf(nD, bf2f((unsigned short)(hD >> 16)), a1);
    }
    for (; e < e1; e++) {
        int sA = srcs[e];
        float nA = dinv[sA] * dn;
        unsigned int hA = *(const unsigned int*)(h + (size_t)sA * 128 + c);
        a0 = fmaf(nA, bf2f((unsigned short)(hA & 0xffffu)), a0);
        a1 = fmaf(nA, bf2f((unsigned short)(hA >> 16)), a1);
    }
    a0 = fmaxf(a0, 0.0f);
    a1 = fmaxf(a1, 0.0f);
    unsigned int o = (unsigned int)f2bf_rne(a0) | ((unsigned int)f2bf_rne(a1) << 16);
    __builtin_nontemporal_store(o, (unsigned int*)(r1 + (size_t)n * 128 + c));
}

// ---------------- fused conv2-agg + pool: wave-per-strip, register segment-sum, atomic flush ----------------
__global__ __launch_bounds__(256) void k_g2p(const unsigned short* __restrict__ r1,
                                             const float* __restrict__ dinv,
                                             const int* __restrict__ row_ptr, const int* __restrict__ srcs,
                                             const int* __restrict__ batch,
                                             float* __restrict__ P) {
    int gw = (blockIdx.x * 256 + threadIdx.x) >> 6;
    int lane = threadIdx.x & 63;
    if (gw >= N_NODES / STRIP) return;
    int n0 = gw * STRIP;
    int c = lane * 2;
    float a0 = 0.0f, a1 = 0.0f;
    int cur_g = batch[n0];
    for (int n = n0; n < n0 + STRIP; n++) {
        int bg = batch[n];
        if (bg != cur_g) {
            atomicAdd(&P[(size_t)cur_g * 128 + c], a0);
            atomicAdd(&P[(size_t)cur_g * 128 + c + 1], a1);
            a0 = a1 = 0.0f;
            cur_g = bg;
        }
        float dn = dinv[n];
        float s2 = dn * dn;
        unsigned int hv = *(const unsigned int*)(r1 + (size_t)n * 128 + c);
        a0 = fmaf(s2, bf2f((unsigned short)(hv & 0xffffu)), a0);
        a1 = fmaf(s2, bf2f((unsigned short)(hv >> 16)), a1);
        int e0 = row_ptr[n], e1 = row_ptr[n + 1];
        int e = e0;
        for (; e + 4 <= e1; e += 4) {
            int sA = srcs[e], sB = srcs[e + 1], sC = srcs[e + 2], sD = srcs[e + 3];
            float nA = dinv[sA] * dn, nB = dinv[sB] * dn, nC = dinv[sC] * dn, nD = dinv[sD] * dn;
            unsigned int hA = *(const unsigned int*)(r1 + (size_t)sA * 128 + c);
            unsigned int hB = *(const unsigned int*)(r1 + (size_t)sB * 128 + c);
            unsigned int hC = *(const unsigned int*)(r1 + (size_t)sC * 128 + c);
            unsigned int hD = *(const unsigned int*)(r1 + (size_t)sD * 128 + c);
            a0 = fmaf(nA, bf2f((unsigned short)(hA & 0xffffu)), a0);
            a1 = fmaf(nA, bf2f((unsigned short)(hA >> 16)), a1);
            a0 = fmaf(nB, bf2f((unsigned short)(hB & 0xffffu)), a0);
            a1 = fmaf(nB, bf2f((unsigned short)(hB >> 16)), a1);
            a0 = fmaf(nC, bf2f((unsigned short)(hC & 0xffffu)), a0);
            a1 = fmaf(nC, bf2f((unsigned short)(hC >> 16)), a1);
            a0 = fmaf(nD, bf2f((unsigned short)(hD & 0xffffu)), a0);
            a1 = fmaf(nD, bf2f((unsigned short)(hD >> 16)), a1);
        }
        for (; e < e1; e++) {
            int sA = srcs[e];
            float nA = dinv[sA] * dn;
            unsigned int hA = *(const unsigned int*)(r1 + (size_t)sA * 128 + c);
            a0 = fmaf(nA, bf2f((unsigned short)(hA & 0xffffu)), a0);
            a1 = fmaf(nA, bf2f((unsigned short)(hA >> 16)), a1);
        }
    }
    atomicAdd(&P[(size_t)cur_g * 128 + c], a0);
    atomicAdd(&P[(size_t)cur_g * 128 + c + 1], a1);
}

// ---------------- z0 build (hi/lo bf16, K padded to 128): cols 0..63 = P@Wc2 + cnt*bc2 ; 64..74 = solv ----------------
__global__ __launch_bounds__(128) void k_zg(const float* __restrict__ P, const int* __restrict__ gstart,
                                            const float* __restrict__ Wc2, const float* __restrict__ bc2,
                                            const float* __restrict__ solv,
                                            unsigned short* __restrict__ z0h, unsigned short* __restrict__ z0l) {
    int g = blockIdx.x; int c = threadIdx.x;   // c in [0,128)
    float v = 0.0f;
    if (c < 64) {
        const float* pr = P + (size_t)g * 128;
        float s = 0.0f;
        #pragma unroll 8
        for (int k = 0; k < 128; k++) s = fmaf(pr[k], Wc2[k * 64 + c], s);
        v = s + (float)(gstart[g + 1] - gstart[g]) * bc2[c];
    } else if (c < 75) {
        v = solv[g * 11 + (c - 64)];
    }
    unsigned short hi, lo; split_bf(v, hi, lo);
    z0h[(size_t)g * 128 + c] = hi;
    z0l[(size_t)g * 128 + c] = lo;
}

// ---------------- transpose + hi/lo split (64-multiple dims) ----------------
__global__ __launch_bounds__(256) void k_tsplit(const float* __restrict__ W, int R, int C,
                                                unsigned short* __restrict__ Th, unsigned short* __restrict__ Tl) {
    __shared__ float tile[64][65];
    int cb = blockIdx.x * 64, rb = blockIdx.y * 64;
    int tc = threadIdx.x & 63, tr4 = threadIdx.x >> 6;
    #pragma unroll 4
    for (int i = 0; i < 16; i++) {
        int r = tr4 + i * 4;
        tile[r][tc] = W[(size_t)(rb + r) * C + cb + tc];
    }
    __syncthreads();
    #pragma unroll 4
    for (int i = 0; i < 16; i++) {
        int r = tr4 + i * 4;
        float v = tile[tc][r];
        unsigned short hi, lo; split_bf(v, hi, lo);
        size_t o = (size_t)(cb + r) * R + rb + tc;
        Th[o] = hi; Tl[o] = lo;
    }
}

// ---------------- split-bf16 MFMA GEMM: C[M,N] = relu(A @ B^T + bias) ----------------
template<int OMODE>  // 0: fp32 out, 1: bf16 hi/lo out
__global__ __launch_bounds__(256) void k_mfma_split(
        const unsigned short* __restrict__ Ah, const unsigned short* __restrict__ Al,
        const unsigned short* __restrict__ Bh, const unsigned short* __restrict__ Bl,
        const float* __restrict__ bias,
        float* __restrict__ C, unsigned short* __restrict__ Ch, unsigned short* __restrict__ Cl,
        int N, int K) {
    __shared__ short lds[32768];   // 64 KB: 4 tiles [128 rows][64 bf16], swizzled
    const int tid = threadIdx.x;
    const int w = tid >> 6, l = tid & 63;
    const int id = blockIdx.x;
    const int bm = id & 127;
    const int bn = id >> 7;
    const unsigned short* gmat = (w == 0) ? Ah : (w == 1) ? Al : (w == 2) ? Bh : Bl;
    const size_t grow0 = (size_t)((w < 2) ? bm : bn) * 128 + (l >> 3);
    const int koffg = ((l & 7) ^ ((l >> 3) & 7)) * 8;
    const int ldsw = w * 8192;
    const int wm = w >> 1, wn = w & 1;
    const int lane15 = l & 15, lg = l >> 4, l7 = l & 7;
    f32x4 acc[4][4] = {};
    const int NK = K >> 6;
    for (int kt = 0; kt < NK; kt++) {
        const int k0 = kt << 6;
        __syncthreads();
        #pragma unroll
        for (int i = 0; i < 16; i++) {
            const unsigned short* src = gmat + (grow0 + (size_t)i * 8) * (size_t)K + k0 + koffg;
            __builtin_amdgcn_global_load_lds(
                (const __attribute__((address_space(1))) unsigned int*)src,
                (__attribute__((address_space(3))) unsigned int*)&lds[ldsw + i * 512],
                16, 0, 0);
        }
        __syncthreads();
        #pragma unroll
        for (int kh = 0; kh < 2; kh++) {
            const int slot = ((kh * 4 + lg) ^ l7) * 8;
            bf16x8 ahf[4], alf[4], bhf[4], blf[4];
            #pragma unroll
            for (int m = 0; m < 4; m++) {
                int si = (wm * 64 + m * 16 + lane15) * 64 + slot;
                ahf[m] = *(const bf16x8*)&lds[si];
                alf[m] = *(const bf16x8*)&lds[8192 + si];
            }
            #pragma unroll
            for (int n = 0; n < 4; n++) {
                int si = (wn * 64 + n * 16 + lane15) * 64 + slot;
                bhf[n] = *(const bf16x8*)&lds[16384 + si];
                blf[n] = *(const bf16x8*)&lds[24576 + si];
            }
            #pragma unroll
            for (int m = 0; m < 4; m++)
                #pragma unroll
                for (int n = 0; n < 4; n++) {
                    acc[m][n] = __builtin_amdgcn_mfma_f32_16x16x32_bf16(ahf[m], bhf[n], acc[m][n], 0, 0, 0);
                    acc[m][n] = __builtin_amdgcn_mfma_f32_16x16x32_bf16(ahf[m], blf[n], acc[m][n], 0, 0, 0);
                    acc[m][n] = __builtin_amdgcn_mfma_f32_16x16x32_bf16(alf[m], bhf[n], acc[m][n], 0, 0, 0);
                }
        }
    }
    const int row_b = bm * 128 + wm * 64 + lg * 4;
    const int col_b = bn * 128 + wn * 64 + lane15;
    #pragma unroll
    for (int m = 0; m < 4; m++)
        #pragma unroll
        for (int n = 0; n < 4; n++) {
            int col = col_b + n * 16;
            float bv = bias[col];
            #pragma unroll
            for (int j = 0; j < 4; j++) {
                int row = row_b + m * 16 + j;
                float v = fmaxf(acc[m][n][j] + bv, 0.0f);
                size_t o = (size_t)row * N + col;
                if (OMODE == 0) {
                    C[o] = v;
                } else {
                    unsigned short hi, lo; split_bf(v, hi, lo);
                    Ch[o] = hi; Cl[o] = lo;
                }
            }
        }
}

// ---------------- final heads reduce ----------------
__global__ __launch_bounds__(256) void k_heads_out(const float* __restrict__ a,
                                                   const float* __restrict__ Wh2,
                                                   const float* __restrict__ bh2,
                                                   float* __restrict__ out) {
    int i = blockIdx.x * 256 + threadIdx.x;
    if (i >= N_GRAPHS * 6) return;
    int g = i / 6, h = i % 6;
    const float* ap = a + (size_t)g * 256 + h * 32;
    const float* wp = Wh2 + h * 32;
    float s = 0.0f;
    #pragma unroll
    for (int k = 0; k < 32; k++) s = fmaf(ap[k], wp[k], s);
    out[i] = s + bh2[h];
}

extern "C" void kernel_launch(void* const* d_in, const int* in_sizes, int n_in,
                              void* d_out, int out_size, void* d_ws, size_t ws_size,
                              hipStream_t stream) {
    const float* x    = (const float*)d_in[0];
    const int*   esrc = (const int*)d_in[1];
    const int*   edst = (const int*)d_in[2];
    const int*   batch= (const int*)d_in[3];
    const float* solv = (const float*)d_in[4];
    const float* Wc1  = (const float*)d_in[5];
    const float* bc1  = (const float*)d_in[6];
    const float* Wc2  = (const float*)d_in[7];
    const float* bc2  = (const float*)d_in[8];
    const float* W1   = (const float*)d_in[9];
    const float* b1   = (const float*)d_in[10];
    const float* W2   = (const float*)d_in[11];
    const float* b2   = (const float*)d_in[12];
    const float* W3   = (const float*)d_in[13];
    const float* b3   = (const float*)d_in[14];
    const float* Wh1  = (const float*)d_in[15];
    const float* bh1  = (const float*)d_in[16];
    const float* Wh2  = (const float*)d_in[17];
    const float* bh2  = (const float*)d_in[18];
    float* out = (float*)d_out;

    // workspace layout (floats)
    float* ws    = (float*)d_ws;
    float* bufA  = ws;                             // 64,000,000 f
    float* bufB  = bufA + 64000000;                // 64,000,000 f
    float* dinv  = bufB + 64000000;                // 524,288 f
    float* bh1p  = dinv + 524288;                  // 256 f
    int* counts  = (int*)(bh1p + 256);             // 500,000
    int* row_ptr = counts + N_NODES;               // 500,224
    int* cursor  = row_ptr + 500224;               // 500,000
    int* srcs    = cursor + N_NODES;               // 2,000,000
    int* bsum    = srcs + N_EDGES;                 // 256
    int* boff    = bsum + 256;                     // 256
    int* gstart  = boff + 256;                     // 16,640
    float* P     = bufB + 61902848;                // 2,097,152 f (tail of bufB)

    // conv activations / staging
    unsigned short* h_bf = (unsigned short*)bufA;  // [500k,128] u16 (bufA[0:32M f))
    unsigned short* r1   = (unsigned short*)bufB;  // [500k,128] u16 (bufB[0:32M f))
    unsigned short* wc1h = (unsigned short*)(bufA + 60000000);  // 24,576 u16
    unsigned short* wc1l = wc1h + 128 * KC1;                    // 24,576 u16

    // MLP hi/lo activations & weights (timeline-disjoint reuse)
    unsigned short* z1h  = (unsigned short*)bufB;               // after r1 dead
    unsigned short* z1l  = (unsigned short*)(bufB + 16800000);
    unsigned short* z2h  = (unsigned short*)bufA;               // after h_bf dead
    unsigned short* z2l  = (unsigned short*)(bufA + 8400000);
    unsigned short* z3h  = (unsigned short*)(bufB + 34000000);  // 2.1M u16
    unsigned short* z3l  = (unsigned short*)(bufB + 35100000);
    unsigned short* z0h  = (unsigned short*)(bufA + 20000000);  // [16384,128] u16
    unsigned short* z0l  = (unsigned short*)(bufA + 21100000);
    unsigned short* w1th = (unsigned short*)(bufA + 22200000);  // [2048,128] u16
    unsigned short* w1tl = (unsigned short*)(bufA + 22400000);
    unsigned short* whh  = (unsigned short*)(bufA + 22600000);  // [256,128] u16
    unsigned short* whl  = (unsigned short*)(bufA + 22700000);
    unsigned short* w2th = (unsigned short*)(bufA + 33000000);  // [1024,2048] u16
    unsigned short* w2tl = (unsigned short*)(bufA + 34100000);
    unsigned short* w3th = (unsigned short*)(bufA + 35200000);  // [128,1024] u16
    unsigned short* w3tl = (unsigned short*)(bufA + 35300000);
    float* ab = bufA + 36000000;                                // [16384,256] f

    // 1) CSR build + dinv + graph segments + P zero
    k_zero_counts<<<(N_NODES + 255) / 256, 256, 0, stream>>>(counts);
    k_hist<<<(N_EDGES + 255) / 256, 256, 0, stream>>>(edst, counts);
    k_scan_reduce<<<SCAN_NBLK, 256, 0, stream>>>(counts, bsum);
    k_scan_bsum<<<1, 256, 0, stream>>>(bsum, boff, row_ptr);
    k_scan_final<<<SCAN_NBLK, 256, 0, stream>>>(counts, boff, row_ptr, cursor, dinv);
    k_fill<<<(N_EDGES + 255) / 256, 256, 0, stream>>>(esrc, edst, cursor, srcs);
    k_gstart<<<(N_GRAPHS + 256) / 256, 256, 0, stream>>>(batch, gstart);
    k_zero_P<<<(N_GRAPHS * 128) / 256, 256, 0, stream>>>(P);

    // 2) conv1 via MFMA (fused x->bf16 staging, A prefetch) ; Wc1 -> hi/lo
    k_wc1split<<<(128 * KC1 + 255) / 256, 256, 0, stream>>>(Wc1, wc1h, wc1l);
    k_mfma_conv1<<<(N_NODES + 127) / 128, 256, 0, stream>>>(x, wc1h, wc1l, h_bf);

    // gather+relu -> r1 (bf16, nontemporal store)
    k_gather1<<<(N_NODES * 64) / 256, 256, 0, stream>>>(h_bf, dinv, bc1, row_ptr, srcs, r1);

    // 3) fused conv2-agg + pool -> P
    k_g2p<<<((N_NODES / STRIP) * 64 + 255) / 256, 256, 0, stream>>>(r1, dinv, row_ptr, srcs, batch, P);

    // weight transposes+splits (h_bf region dead after gather1)
    k_tsplit<<<dim3(1024 / 64, 2048 / 64), 256, 0, stream>>>(W2, 2048, 1024, w2th, w2tl);
    k_tsplit<<<dim3(128 / 64, 1024 / 64), 256, 0, stream>>>(W3, 1024, 128, w3th, w3tl);
    k_w1split<<<(2048 * 128) / 256, 256, 0, stream>>>(W1, w1th, w1tl);
    k_whsplit<<<(256 * 128) / 256, 256, 0, stream>>>(Wh1, whh, whl);
    k_bh1pad<<<1, 256, 0, stream>>>(bh1, bh1p);

    // z0 = [pool@Wc2 + cnt*bc2 | solv | 0] as hi/lo bf16, K padded to 128
    k_zg<<<N_GRAPHS, 128, 0, stream>>>(P, gstart, Wc2, bc2, solv, z0h, z0l);

    // 4) MLP — all split-bf16 MFMA
    // W1 (K=128 padded) -> z1 hi/lo
    k_mfma_split<1><<<(2048 / 128) * (N_GRAPHS / 128), 256, 0, stream>>>(
        z0h, z0l, w1th, w1tl, b1, nullptr, z1h, z1l, 2048, 128);
    // W2 (K=2048) -> z2 hi/lo
    k_mfma_split<1><<<(1024 / 128) * (N_GRAPHS / 128), 256, 0, stream>>>(
        z1h, z1l, w2th, w2tl, b2, nullptr, z2h, z2l, 1024, 2048);
    // W3 (K=1024) -> z3 hi/lo
    k_mfma_split<1><<<(128 / 128) * (N_GRAPHS / 128), 256, 0, stream>>>(
        z2h, z2l, w3th, w3tl, b3, nullptr, z3h, z3l, 128, 1024);
    // heads layer 1 (K=128) -> ab fp32
    k_mfma_split<0><<<(256 / 128) * (N_GRAPHS / 128), 256, 0, stream>>>(
        z3h, z3l, whh, whl, bh1p, ab, nullptr, nullptr, 256, 128);

    // 5) final heads reduce
    k_heads_out<<<(N_GRAPHS * 6 + 255) / 256, 256, 0, stream>>>(ab, Wh2, bh2, out);
}